// Round 13
// baseline (386.661 us; speedup 1.0000x reference)
//
#include <hip/hip_runtime.h>

#define NN 50000
#define EE 800000
#define NDIM 128
#define EDIM 32
#define HH 64
#define NBLK 196        // ceil(NN/256)
#define NB64 782        // ceil(NN/64)

typedef unsigned short u16;
typedef unsigned int u32;
typedef u16 u16x8 __attribute__((ext_vector_type(8)));
typedef __bf16 bf16x8 __attribute__((ext_vector_type(8)));
typedef float f32x4 __attribute__((ext_vector_type(4)));

// ws layout (bytes) — ~96 MB total (ws = 400 MB confirmed by poison fill)
#define OFF_H32  0ull                        // NN*HH f32 hsum accumulator
#define OFF_P    12800000ull                 // NN*HH f32, PERMUTED: [node][r16*4+nt]
#define OFF_RS   25600000ull                 // NN*HH u16: r_src = h@fin_W1_top (bf16)
#define OFF_RD   32000000ull                 // NN*HH u16: r_dst = h@fin_W1_bot + fin_b1
#define OFF_NWF  38400000ull                 // 16,384
#define OFF_W1T  (OFF_NWF + 16384ull)        // 32,768
#define OFF_W1E  (OFF_W1T + 32768ull)        // 16,384
#define OFF_W2F  (OFF_W1E + 16384ull)        // 32,768
#define OFF_FWS  (OFF_W2F + 32768ull)        // 8,192
#define OFF_FWD  (OFF_FWS + 8192ull)         // 8,192
#define OFF_B1P  (OFF_FWD + 8192ull)         // 1,024
#define OFF_CUR  (OFF_B1P + 1024ull)         // 200,704
#define OFF_DEG  (OFF_CUR + 200704ull)       // 200,704
#define OFF_BSUM (OFF_DEG + 200704ull)       // 1,024
#define OFF_SD   (OFF_BSUM + 1024ull)        // EE*4 (packed src<<16|dst, sorted)
#define OFF_EAP  (OFF_SD + 3200000ull)       // EE*32*2 = 51,200,000 (bf16, sorted)
#define WS_NEED  (OFF_EAP + 51200000ull)

#define LDX 136   // u16 stride (node_enc X tile)
#define LHS 68    // f32 stride (node-level f32 tiles)
#define SMS 66    // f32 stride of message tile

__device__ __forceinline__ u16 f2bf(float f) {
  unsigned int u = __builtin_bit_cast(unsigned int, f);
  u += 0x7fffu + ((u >> 16) & 1u);
  return (u16)(u >> 16);
}
__device__ __forceinline__ float bf2f(u16 h) {
  unsigned int u = ((unsigned int)h) << 16;
  return __builtin_bit_cast(float, u);
}
__device__ __forceinline__ void split8(const f32x4 a0, const f32x4 a1,
                                       bf16x8& hi, bf16x8& lo) {
  u16x8 h_, l_;
#pragma unroll
  for (int j = 0; j < 4; ++j) {
    float v = a0[j]; u16 hb = f2bf(v); h_[j] = hb; l_[j] = f2bf(v - bf2f(hb));
    v = a1[j]; hb = f2bf(v); h_[4 + j] = hb; l_[4 + j] = f2bf(v - bf2f(hb));
  }
  hi = __builtin_bit_cast(bf16x8, h_);
  lo = __builtin_bit_cast(bf16x8, l_);
}

// ---------------------------------------------------------------- setup ----
// frag(kk,nt,lane,j) = W[kk*32 + (lane>>4)*8 + j][nt*16 + (lane&15)]
__global__ __launch_bounds__(256)
void setup_kernel(const float* __restrict__ node_W, const float* __restrict__ edge_W,
                  const float* __restrict__ edge_b, const float* __restrict__ W1,
                  const float* __restrict__ b1, const float* __restrict__ W2,
                  const float* __restrict__ fin_W1,
                  u16* __restrict__ nWf, u16* __restrict__ W1T, u16* __restrict__ W1E,
                  u16* __restrict__ W2f, u16* __restrict__ fWs, u16* __restrict__ fWd,
                  float* __restrict__ b1p)
{
  const int tid = threadIdx.x;
  const int blk = blockIdx.x;
  if (blk == 0) {
    for (int idx = tid; idx < 8192; idx += 256) {
      int j = idx & 7, l = (idx >> 3) & 63, nt = (idx >> 9) & 3, kk = idx >> 11;
      int k = kk * 32 + (l >> 4) * 8 + j, n = nt * 16 + (l & 15);
      nWf[idx] = f2bf(node_W[k * HH + n]);
    }
  } else if (blk == 5) {
    for (int idx = tid; idx < 4096; idx += 256) {
      int j = idx & 7, l = (idx >> 3) & 63, nt = (idx >> 9) & 3, kk = idx >> 11;
      int k = kk * 32 + (l >> 4) * 8 + j, n = nt * 16 + (l & 15);
      fWs[idx] = f2bf(fin_W1[k * HH + n]);
      fWd[idx] = f2bf(fin_W1[(k + 64) * HH + n]);
    }
  } else {
    const int layer = blk - 1;
    __shared__ float e1[32 * 64];
    const float* W1l = W1 + (size_t)layer * NDIM * HH;
    for (int idx = tid; idx < 2048; idx += 256) {
      int a = idx >> 6, n = idx & 63;
      float s = 0.f;
      for (int k = 0; k < 64; ++k) s += edge_W[a * HH + k] * W1l[(64 + k) * HH + n];
      e1[a * 64 + n] = s;
    }
    if (tid < 64) {
      float s = b1[layer * HH + tid];
      for (int k = 0; k < 64; ++k) s += edge_b[k] * W1l[(64 + k) * HH + tid];
      b1p[layer * HH + tid] = s;
    }
    __syncthreads();
    for (int idx = tid; idx < 4096; idx += 256) {
      int j = idx & 7, l = (idx >> 3) & 63, nt = (idx >> 9) & 3, kk = idx >> 11;
      int k = kk * 32 + (l >> 4) * 8 + j, n = nt * 16 + (l & 15);
      W1T[layer * 4096 + idx] = f2bf(W1l[k * HH + n]);
    }
    for (int idx = tid; idx < 2048; idx += 256) {
      int j = idx & 7, l = (idx >> 3) & 63, nt = idx >> 9;
      int k = (l >> 4) * 8 + j, n = nt * 16 + (l & 15);
      W1E[layer * 2048 + idx] = f2bf(e1[k * 64 + n]);
    }
    for (int idx = tid; idx < 4096; idx += 256) {
      int j = idx & 7, l = (idx >> 3) & 63, nt = (idx >> 9) & 3, kk = idx >> 11;
      int k = kk * 32 + (l >> 4) * 8 + j, n = nt * 16 + (l & 15);
      W2f[layer * 4096 + idx] = f2bf(W2[((size_t)layer * HH + k) * HH + n]);
    }
  }
}

// ------------------------------------------------------- counting sort -----
__global__ __launch_bounds__(256)
void zero2(int* __restrict__ cnt, float* __restrict__ h32)
{
  int t = blockIdx.x * 256 + threadIdx.x;
  if (t < 50176) cnt[t] = 0;
  if (t < EE) {
    f32x4 z = (f32x4){0.f, 0.f, 0.f, 0.f};
    *reinterpret_cast<f32x4*>(h32 + (size_t)t * 4) = z;
  }
}

__global__ __launch_bounds__(256)
void hist_kernel(const int* __restrict__ ei, int* __restrict__ cnt)
{
  int e = blockIdx.x * 256 + threadIdx.x;
  if (e < EE) atomicAdd(&cnt[ei[EE + e]], 1);
}

__global__ __launch_bounds__(256)
void chunk_sum(const int* __restrict__ cnt, int* __restrict__ bsum)
{
  int i = blockIdx.x * 256 + threadIdx.x;
  int v = (i < NN) ? cnt[i] : 0;
  int lane = threadIdx.x & 63, wv = threadIdx.x >> 6;
#pragma unroll
  for (int m = 1; m < 64; m <<= 1) v += __shfl_xor(v, m, 64);
  __shared__ int ws4[4];
  if (lane == 0) ws4[wv] = v;
  __syncthreads();
  if (threadIdx.x == 0) bsum[blockIdx.x] = ws4[0] + ws4[1] + ws4[2] + ws4[3];
}

__global__ __launch_bounds__(64)
void scan_small(int* __restrict__ bsum)
{
  int lane = threadIdx.x;
  int carry = 0;
  for (int r = 0; r < (NBLK + 63) / 64; ++r) {
    int idx = r * 64 + lane;
    int v = (idx < NBLK) ? bsum[idx] : 0;
    int s = v;
#pragma unroll
    for (int d = 1; d < 64; d <<= 1) {
      int t = __shfl_up(s, d, 64);
      if (lane >= d) s += t;
    }
    if (idx < NBLK) bsum[idx] = s - v + carry;
    carry += __shfl(s, 63, 64);
  }
}

__global__ __launch_bounds__(256)
void scan_write(int* __restrict__ cursor, const int* __restrict__ bsum,
                float* __restrict__ degf)
{
  int i = blockIdx.x * 256 + threadIdx.x;
  int v = (i < NN) ? cursor[i] : 0;
  int lane = threadIdx.x & 63, wv = threadIdx.x >> 6;
  int s = v;
#pragma unroll
  for (int d = 1; d < 64; d <<= 1) {
    int t = __shfl_up(s, d, 64);
    if (lane >= d) s += t;
  }
  __shared__ int ws4[4];
  if (lane == 63) ws4[wv] = s;
  __syncthreads();
  int wo = 0;
  for (int w = 0; w < wv; ++w) wo += ws4[w];
  if (i < NN) {
    cursor[i] = s - v + wo + bsum[blockIdx.x];
    degf[i] = (float)v;
  }
}

// scatter_pay: coalesced ei + edge_attr reads; NONTEMPORAL random writes of
// packed (src,dst) and the bf16 ea row to the sorted position.
__global__ __launch_bounds__(256)
void scatter_pay(const int* __restrict__ ei, const float* __restrict__ edge_attr,
                 int* __restrict__ cursor, u32* __restrict__ sd, u16* __restrict__ eap)
{
  int e = blockIdx.x * 256 + threadIdx.x;
  if (e >= EE) return;
  int s = ei[e];
  int d = ei[EE + e];
  const f32x4* pa = reinterpret_cast<const f32x4*>(edge_attr + (size_t)e * EDIM);
  f32x4 v[8];
#pragma unroll
  for (int q = 0; q < 8; ++q) v[q] = pa[q];
  u16x8 o[4];
#pragma unroll
  for (int q = 0; q < 4; ++q)
#pragma unroll
    for (int j = 0; j < 4; ++j) {
      o[q][j] = f2bf(v[2 * q][j]);
      o[q][4 + j] = f2bf(v[2 * q + 1][j]);
    }
  int pos = atomicAdd(&cursor[d], 1);
  __builtin_nontemporal_store(((u32)s << 16) | (u32)d, &sd[pos]);
  u16* po = eap + (size_t)pos * EDIM;
#pragma unroll
  for (int q = 0; q < 4; ++q)
    __builtin_nontemporal_store(o[q], reinterpret_cast<u16x8*>(po + q * 8));
}

// ------------------------------- node enc: h0 (f32) -> p0 (split GEMM) -----
// p storage is PERMUTED: p[node*64 + r16*4 + nt] == logical col nt*16+r16.
__global__ __launch_bounds__(256, 2)
void node_enc(const float* __restrict__ x, const u16* __restrict__ nWf,
              const float* __restrict__ node_b, const u16* __restrict__ W1T,
              float* __restrict__ p)
{
  __shared__ __align__(16) char ebuf[64 * 272];   // Xs (u16 LDX) / Hs (f32 LHS)
  u16* Xs = reinterpret_cast<u16*>(ebuf);
  float* Hs = reinterpret_cast<float*>(ebuf);
  const int tid = threadIdx.x;
  const int base = blockIdx.x * 64;
  const int lane = tid & 63, wv = tid >> 6;
  const int r16 = lane & 15, kg = lane >> 4;

  bf16x8 Bf[4][4];
#pragma unroll
  for (int kk = 0; kk < 4; ++kk)
#pragma unroll
    for (int nt = 0; nt < 4; ++nt)
      Bf[kk][nt] = *reinterpret_cast<const bf16x8*>(nWf + ((kk * 4 + nt) * 64 + lane) * 8);
  float bias[4];
#pragma unroll
  for (int nt = 0; nt < 4; ++nt) bias[nt] = node_b[nt * 16 + r16];

#pragma unroll
  for (int it = 0; it < 4; ++it) {
    int s = it * 256 + tid;
    int r = s >> 4, c = (s & 15) * 8;
    int node = base + r;
    u16x8 o;
    if (node < NN) {
      const f32x4* px = reinterpret_cast<const f32x4*>(x + (size_t)node * NDIM + c);
      f32x4 v0 = px[0], v1 = px[1];
#pragma unroll
      for (int j = 0; j < 4; ++j) { o[j] = f2bf(v0[j]); o[4 + j] = f2bf(v1[j]); }
    } else {
#pragma unroll
      for (int j = 0; j < 8; ++j) o[j] = 0;
    }
    *reinterpret_cast<u16x8*>(&Xs[r * LDX + c]) = o;
  }
  __syncthreads();

  f32x4 acc[4];
#pragma unroll
  for (int nt = 0; nt < 4; ++nt) acc[nt] = (f32x4){0.f, 0.f, 0.f, 0.f};
#pragma unroll
  for (int kk = 0; kk < 4; ++kk) {
    bf16x8 a = *reinterpret_cast<const bf16x8*>(&Xs[(wv * 16 + r16) * LDX + kk * 32 + kg * 8]);
#pragma unroll
    for (int nt = 0; nt < 4; ++nt)
      acc[nt] = __builtin_amdgcn_mfma_f32_16x16x32_bf16(a, Bf[kk][nt], acc[nt], 0, 0, 0);
  }
  __syncthreads();

#pragma unroll
  for (int nt = 0; nt < 4; ++nt)
#pragma unroll
    for (int j = 0; j < 4; ++j)
      Hs[(wv * 16 + kg * 4 + j) * LHS + nt * 16 + r16] = acc[nt][j] + bias[nt];
  __syncthreads();

  bf16x8 Bt[2][4];
#pragma unroll
  for (int kk = 0; kk < 2; ++kk)
#pragma unroll
    for (int nt = 0; nt < 4; ++nt)
      Bt[kk][nt] = *reinterpret_cast<const bf16x8*>(W1T + ((kk * 4 + nt) * 64 + lane) * 8);

  f32x4 acc2[4];
#pragma unroll
  for (int nt = 0; nt < 4; ++nt) acc2[nt] = (f32x4){0.f, 0.f, 0.f, 0.f};
#pragma unroll
  for (int kk = 0; kk < 2; ++kk) {
    const f32x4* pa = reinterpret_cast<const f32x4*>(&Hs[(wv * 16 + r16) * LHS + kk * 32 + kg * 8]);
    f32x4 a0 = pa[0], a1 = pa[1];
    bf16x8 hi, lo;
    split8(a0, a1, hi, lo);
#pragma unroll
    for (int nt = 0; nt < 4; ++nt) {
      acc2[nt] = __builtin_amdgcn_mfma_f32_16x16x32_bf16(hi, Bt[kk][nt], acc2[nt], 0, 0, 0);
      acc2[nt] = __builtin_amdgcn_mfma_f32_16x16x32_bf16(lo, Bt[kk][nt], acc2[nt], 0, 0, 0);
    }
  }
#pragma unroll
  for (int j = 0; j < 4; ++j) {
    int node = base + wv * 16 + kg * 4 + j;
    if (node < NN) {
      f32x4 w;
#pragma unroll
      for (int nt = 0; nt < 4; ++nt) w[nt] = acc2[nt][j];
      *reinterpret_cast<f32x4*>(p + (size_t)node * HH + r16 * 4) = w;
    }
  }
}

// --------------------- message: relu(p_src+p_dst+ea@W1e'+b1'), aggregate ---
__global__ __launch_bounds__(256, 8)
void msg2(const u32* __restrict__ sd, const u16* __restrict__ eap,
          const float* __restrict__ p, float* __restrict__ h32,
          const u16* __restrict__ W1E, const float* __restrict__ b1p, int layer)
{
  __shared__ float Sm[64 * SMS];
  __shared__ u32 sd_s[64];
  __shared__ int segpos[64];
  __shared__ int segn;

  const int tid = threadIdx.x;
  const int base = blockIdx.x * 64;
  const int lane = tid & 63, wv = tid >> 6;
  const int r16 = lane & 15, kg = lane >> 4;

  if (tid < 64) sd_s[tid] = sd[base + tid];

  bf16x8 B1[4];
  const u16* w1 = W1E + layer * 2048;
#pragma unroll
  for (int nt = 0; nt < 4; ++nt)
    B1[nt] = *reinterpret_cast<const bf16x8*>(w1 + (nt * 64 + lane) * 8);
  float b1v[4];
#pragma unroll
  for (int nt = 0; nt < 4; ++nt) b1v[nt] = b1p[layer * HH + nt * 16 + r16];

  // A-frag: pre-sorted bf16 edge_attr, direct 16B streaming load
  bf16x8 af = *reinterpret_cast<const bf16x8*>(
      eap + (size_t)(base + wv * 16 + r16) * EDIM + kg * 8);
  __syncthreads();

  if (wv == 0) {
    int dme = sd_s[lane] & 0xffff;
    int dpr = (lane > 0) ? (sd_s[lane - 1] & 0xffff) : -1;
    bool st = (dme != dpr);
    unsigned long long m = __ballot(st);
    if (st) {
      int rk = __popcll(m & ((1ull << lane) - 1ull));
      segpos[rk] = lane;
    }
    if (lane == 0) segn = __popcll(m);
  }

  // C init: p[src]+p[dst]+b1' via permuted-layout float4 gathers
  f32x4 acc[4];
#pragma unroll
  for (int j = 0; j < 4; ++j) {
    int row = wv * 16 + kg * 4 + j;
    u32 w = sd_s[row];
    const f32x4 a = *reinterpret_cast<const f32x4*>(p + (size_t)(w >> 16) * HH + r16 * 4);
    const f32x4 b = *reinterpret_cast<const f32x4*>(p + (size_t)(w & 0xffff) * HH + r16 * 4);
#pragma unroll
    for (int nt = 0; nt < 4; ++nt) acc[nt][j] = a[nt] + b[nt] + b1v[nt];
  }

#pragma unroll
  for (int nt = 0; nt < 4; ++nt)
    acc[nt] = __builtin_amdgcn_mfma_f32_16x16x32_bf16(af, B1[nt], acc[nt], 0, 0, 0);

#pragma unroll
  for (int nt = 0; nt < 4; ++nt)
#pragma unroll
    for (int j = 0; j < 4; ++j)
      Sm[(wv * 16 + kg * 4 + j) * SMS + nt * 16 + r16] = fmaxf(acc[nt][j], 0.f);
  __syncthreads();

  int ns = segn;
  for (int s = wv; s < ns; s += 4) {
    int r0 = segpos[s];
    int r1 = (s + 1 < ns) ? segpos[s + 1] : 64;
    float sum = 0.f;
    for (int r = r0; r < r1; ++r) sum += Sm[r * SMS + lane];
    unsafeAtomicAdd(&h32[(size_t)(sd_s[r0] & 0xffff) * HH + lane], sum);
  }
}

// ------ node update: h = hsum@W2 + deg*b2 (split); p' = h@W1top' (split);
// ------ on layer 3: r_src = h@fin_W1_top, r_dst = h@fin_W1_bot + fin_b1 ----
__global__ __launch_bounds__(256, 2)
void node_update(float* __restrict__ h32, const float* __restrict__ degf,
                 const u16* __restrict__ W2f, const float* __restrict__ b2a,
                 const u16* __restrict__ W1T, float* __restrict__ p,
                 const u16* __restrict__ fWs, const u16* __restrict__ fWd,
                 const float* __restrict__ fin_b1,
                 u16* __restrict__ r_src, u16* __restrict__ r_dst, int layer)
{
  __shared__ __align__(16) float Hs[64 * LHS];
  const int tid = threadIdx.x;
  const int base = blockIdx.x * 64;
  const int lane = tid & 63, wv = tid >> 6;
  const int r16 = lane & 15, kg = lane >> 4;

#pragma unroll
  for (int it = 0; it < 2; ++it) {
    int s = it * 256 + tid;
    int r = s >> 3, c = (s & 7) * 8;
    int node = base + r;
    f32x4 v0 = (f32x4){0.f, 0.f, 0.f, 0.f}, v1 = v0;
    if (node < NN) {
      f32x4* ph = reinterpret_cast<f32x4*>(h32 + (size_t)node * HH + c);
      v0 = ph[0]; v1 = ph[1];
      f32x4 z = (f32x4){0.f, 0.f, 0.f, 0.f};
      ph[0] = z; ph[1] = z;
    }
    *reinterpret_cast<f32x4*>(&Hs[r * LHS + c]) = v0;
    *reinterpret_cast<f32x4*>(&Hs[r * LHS + c + 4]) = v1;
  }

  bf16x8 B2[2][4];
  const u16* w2 = W2f + layer * 4096;
#pragma unroll
  for (int kk = 0; kk < 2; ++kk)
#pragma unroll
    for (int nt = 0; nt < 4; ++nt)
      B2[kk][nt] = *reinterpret_cast<const bf16x8*>(w2 + ((kk * 4 + nt) * 64 + lane) * 8);
  float b2v[4];
#pragma unroll
  for (int nt = 0; nt < 4; ++nt) b2v[nt] = b2a[layer * HH + nt * 16 + r16];
  float degj[4];
#pragma unroll
  for (int j = 0; j < 4; ++j) {
    int node = base + wv * 16 + kg * 4 + j;
    degj[j] = (node < NN) ? degf[node] : 0.f;
  }
  __syncthreads();

  // h = hsum @ W2 + deg*b2, split-precision A
  f32x4 acc[4];
#pragma unroll
  for (int nt = 0; nt < 4; ++nt)
#pragma unroll
    for (int j = 0; j < 4; ++j) acc[nt][j] = degj[j] * b2v[nt];
#pragma unroll
  for (int kk = 0; kk < 2; ++kk) {
    const f32x4* pa = reinterpret_cast<const f32x4*>(&Hs[(wv * 16 + r16) * LHS + kk * 32 + kg * 8]);
    f32x4 a0 = pa[0], a1 = pa[1];
    bf16x8 hi, lo;
    split8(a0, a1, hi, lo);
#pragma unroll
    for (int nt = 0; nt < 4; ++nt) {
      acc[nt] = __builtin_amdgcn_mfma_f32_16x16x32_bf16(hi, B2[kk][nt], acc[nt], 0, 0, 0);
      acc[nt] = __builtin_amdgcn_mfma_f32_16x16x32_bf16(lo, B2[kk][nt], acc[nt], 0, 0, 0);
    }
  }

  __syncthreads();
#pragma unroll
  for (int nt = 0; nt < 4; ++nt)
#pragma unroll
    for (int j = 0; j < 4; ++j)
      Hs[(wv * 16 + kg * 4 + j) * LHS + nt * 16 + r16] = acc[nt][j];
  __syncthreads();

  if (layer == 3) {
    bf16x8 Bs[2][4], Bd[2][4];
#pragma unroll
    for (int kk = 0; kk < 2; ++kk)
#pragma unroll
      for (int nt = 0; nt < 4; ++nt) {
        Bs[kk][nt] = *reinterpret_cast<const bf16x8*>(fWs + ((kk * 4 + nt) * 64 + lane) * 8);
        Bd[kk][nt] = *reinterpret_cast<const bf16x8*>(fWd + ((kk * 4 + nt) * 64 + lane) * 8);
      }
    float fb1v[4];
#pragma unroll
    for (int nt = 0; nt < 4; ++nt) fb1v[nt] = fin_b1[nt * 16 + r16];

    f32x4 as_[4], ad_[4];
#pragma unroll
    for (int nt = 0; nt < 4; ++nt) {
      as_[nt] = (f32x4){0.f, 0.f, 0.f, 0.f};
#pragma unroll
      for (int j = 0; j < 4; ++j) ad_[nt][j] = fb1v[nt];
    }
#pragma unroll
    for (int kk = 0; kk < 2; ++kk) {
      const f32x4* pa = reinterpret_cast<const f32x4*>(&Hs[(wv * 16 + r16) * LHS + kk * 32 + kg * 8]);
      f32x4 a0 = pa[0], a1 = pa[1];
      bf16x8 hi, lo;
      split8(a0, a1, hi, lo);
#pragma unroll
      for (int nt = 0; nt < 4; ++nt) {
        as_[nt] = __builtin_amdgcn_mfma_f32_16x16x32_bf16(hi, Bs[kk][nt], as_[nt], 0, 0, 0);
        as_[nt] = __builtin_amdgcn_mfma_f32_16x16x32_bf16(lo, Bs[kk][nt], as_[nt], 0, 0, 0);
        ad_[nt] = __builtin_amdgcn_mfma_f32_16x16x32_bf16(hi, Bd[kk][nt], ad_[nt], 0, 0, 0);
        ad_[nt] = __builtin_amdgcn_mfma_f32_16x16x32_bf16(lo, Bd[kk][nt], ad_[nt], 0, 0, 0);
      }
    }
#pragma unroll
    for (int j = 0; j < 4; ++j) {
      int node = base + wv * 16 + kg * 4 + j;
      if (node < NN) {
#pragma unroll
        for (int nt = 0; nt < 4; ++nt) {
          r_src[(size_t)node * HH + nt * 16 + r16] = f2bf(as_[nt][j]);
          r_dst[(size_t)node * HH + nt * 16 + r16] = f2bf(ad_[nt][j]);
        }
      }
    }
    return;
  }

  // p' = h @ W1top[layer+1] (split)
  bf16x8 Bt[2][4];
  const u16* wt = W1T + (layer + 1) * 4096;
#pragma unroll
  for (int kk = 0; kk < 2; ++kk)
#pragma unroll
    for (int nt = 0; nt < 4; ++nt)
      Bt[kk][nt] = *reinterpret_cast<const bf16x8*>(wt + ((kk * 4 + nt) * 64 + lane) * 8);

  f32x4 acc2[4];
#pragma unroll
  for (int nt = 0; nt < 4; ++nt) acc2[nt] = (f32x4){0.f, 0.f, 0.f, 0.f};
#pragma unroll
  for (int kk = 0; kk < 2; ++kk) {
    const f32x4* pa = reinterpret_cast<const f32x4*>(&Hs[(wv * 16 + r16) * LHS + kk * 32 + kg * 8]);
    f32x4 a0 = pa[0], a1 = pa[1];
    bf16x8 hi, lo;
    split8(a0, a1, hi, lo);
#pragma unroll
    for (int nt = 0; nt < 4; ++nt) {
      acc2[nt] = __builtin_amdgcn_mfma_f32_16x16x32_bf16(hi, Bt[kk][nt], acc2[nt], 0, 0, 0);
      acc2[nt] = __builtin_amdgcn_mfma_f32_16x16x32_bf16(lo, Bt[kk][nt], acc2[nt], 0, 0, 0);
    }
  }
#pragma unroll
  for (int j = 0; j < 4; ++j) {
    int node = base + wv * 16 + kg * 4 + j;
    if (node < NN) {
      f32x4 w;
#pragma unroll
      for (int nt = 0; nt < 4; ++nt) w[nt] = acc2[nt][j];
      *reinterpret_cast<f32x4*>(p + (size_t)node * HH + r16 * 4) = w;
    }
  }
}

// -- final: 4 threads/edge, original order; coalesced 128B row-gathers ------
__global__ __launch_bounds__(256)
void final2(const int* __restrict__ ei, const u16* __restrict__ r_src,
            const u16* __restrict__ r_dst, const float* __restrict__ fin_W2,
            const float* __restrict__ fin_b2, float* __restrict__ out)
{
  __shared__ float w2s[64];
  const int tid = threadIdx.x;
  if (tid < 64) w2s[tid] = fin_W2[tid];
  __syncthreads();
  int t = blockIdx.x * 256 + tid;
  int e = t >> 2, q = t & 3;            // 4 threads per edge, 16 cols each
  if (e >= EE) return;
  int s = ei[e], d = ei[EE + e];
  const u16x8* prs = reinterpret_cast<const u16x8*>(r_src + (size_t)s * HH + q * 16);
  const u16x8* prd = reinterpret_cast<const u16x8*>(r_dst + (size_t)d * HH + q * 16);
  float acc = 0.f;
#pragma unroll
  for (int h = 0; h < 2; ++h) {
    u16x8 a = prs[h], b = prd[h];
#pragma unroll
    for (int j = 0; j < 8; ++j) {
      float v = bf2f(a[j]) + bf2f(b[j]);
      acc += fmaxf(v, 0.f) * w2s[q * 16 + h * 8 + j];
    }
  }
  acc += __shfl_xor(acc, 1, 64);
  acc += __shfl_xor(acc, 2, 64);
  if (q == 0) out[e] = acc + fin_b2[0];
}

// ---------------------------------------------------------------- launch ---
extern "C" void kernel_launch(void* const* d_in, const int* in_sizes, int n_in,
                              void* d_out, int out_size, void* d_ws, size_t ws_size,
                              hipStream_t stream)
{
  const float* x      = (const float*)d_in[0];
  const float* eattr  = (const float*)d_in[1];
  const int*   ei     = (const int*)d_in[2];
  const float* node_W = (const float*)d_in[3];
  const float* node_b = (const float*)d_in[4];
  const float* edge_W = (const float*)d_in[5];
  const float* edge_b = (const float*)d_in[6];
  const float* W1     = (const float*)d_in[7];
  const float* b1     = (const float*)d_in[8];
  const float* W2     = (const float*)d_in[9];
  const float* b2     = (const float*)d_in[10];
  const float* fin_W1 = (const float*)d_in[11];
  const float* fin_b1 = (const float*)d_in[12];
  const float* fin_W2 = (const float*)d_in[13];
  const float* fin_b2 = (const float*)d_in[14];

  char* ws    = (char*)d_ws;
  float* h32  = (float*)(ws + OFF_H32);
  float* p    = (float*)(ws + OFF_P);
  u16* r_src  = (u16*)(ws + OFF_RS);
  u16* r_dst  = (u16*)(ws + OFF_RD);
  u16* nWf    = (u16*)(ws + OFF_NWF);
  u16* W1T    = (u16*)(ws + OFF_W1T);
  u16* W1E    = (u16*)(ws + OFF_W1E);
  u16* W2f    = (u16*)(ws + OFF_W2F);
  u16* fWs    = (u16*)(ws + OFF_FWS);
  u16* fWd    = (u16*)(ws + OFF_FWD);
  float* b1p  = (float*)(ws + OFF_B1P);
  int* cursor = (int*)(ws + OFF_CUR);
  float* degf = (float*)(ws + OFF_DEG);
  int* bsum   = (int*)(ws + OFF_BSUM);
  u32* sd     = (u32*)(ws + OFF_SD);
  u16* eap    = (u16*)(ws + OFF_EAP);

  zero2<<<(EE + 255) / 256, 256, 0, stream>>>(cursor, h32);
  setup_kernel<<<6, 256, 0, stream>>>(node_W, edge_W, edge_b, W1, b1, W2, fin_W1,
                                      nWf, W1T, W1E, W2f, fWs, fWd, b1p);
  node_enc<<<NB64, 256, 0, stream>>>(x, nWf, node_b, W1T, p);

  hist_kernel<<<(EE + 255) / 256, 256, 0, stream>>>(ei, cursor);
  chunk_sum<<<NBLK, 256, 0, stream>>>(cursor, bsum);
  scan_small<<<1, 64, 0, stream>>>(bsum);
  scan_write<<<NBLK, 256, 0, stream>>>(cursor, bsum, degf);
  scatter_pay<<<(EE + 255) / 256, 256, 0, stream>>>(ei, eattr, cursor, sd, eap);

  for (int l = 0; l < 4; ++l) {
    msg2<<<EE / 64, 256, 0, stream>>>(sd, eap, p, h32, W1E, b1p, l);
    node_update<<<NB64, 256, 0, stream>>>(h32, degf, W2f, b2, W1T, p,
                                          fWs, fWd, fin_b1, r_src, r_dst, l);
  }
  final2<<<(EE * 4 + 255) / 256, 256, 0, stream>>>(ei, r_src, r_dst,
                                                   fin_W2, fin_b2, (float*)d_out);
}

// Round 15
// 344.582 us; speedup vs baseline: 1.1221x; 1.1221x over previous
//
#include <hip/hip_runtime.h>

#define NN 50000
#define EE 800000
#define NDIM 128
#define EDIM 32
#define HH 64
#define NBLK 196        // ceil(NN/256)
#define NB64 782        // ceil(NN/64)

typedef unsigned short u16;
typedef unsigned int u32;
typedef u16 u16x8 __attribute__((ext_vector_type(8)));
typedef __bf16 bf16x8 __attribute__((ext_vector_type(8)));
typedef float f32x4 __attribute__((ext_vector_type(4)));

// ws layout (bytes) — ~96 MB total (ws = 400 MB confirmed by poison fill)
#define OFF_H32  0ull                        // NN*HH f32 hsum accumulator
#define OFF_P    12800000ull                 // NN*HH f32, PERMUTED: [node][r16*4+nt]
#define OFF_RS   25600000ull                 // NN*HH u16: r_src = h@fin_W1_top (bf16)
#define OFF_RD   32000000ull                 // NN*HH u16: r_dst = h@fin_W1_bot + fin_b1
#define OFF_NWF  38400000ull                 // 16,384
#define OFF_W1T  (OFF_NWF + 16384ull)        // 32,768
#define OFF_W1E  (OFF_W1T + 32768ull)        // 16,384
#define OFF_W2F  (OFF_W1E + 16384ull)        // 32,768
#define OFF_FWS  (OFF_W2F + 32768ull)        // 8,192
#define OFF_FWD  (OFF_FWS + 8192ull)         // 8,192
#define OFF_B1P  (OFF_FWD + 8192ull)         // 1,024
#define OFF_CUR  (OFF_B1P + 1024ull)         // 200,704
#define OFF_DEG  (OFF_CUR + 200704ull)       // 200,704
#define OFF_BSUM (OFF_DEG + 200704ull)       // 1,024
#define OFF_SD   (OFF_BSUM + 1024ull)        // EE*4 (packed src<<16|dst, sorted)
#define OFF_EAP  (OFF_SD + 3200000ull)       // EE*32*2 = 51,200,000 (bf16, sorted)
#define WS_NEED  (OFF_EAP + 51200000ull)

#define LDX 136   // u16 stride (node_enc X tile)
#define LHS 68    // f32 stride (node-level f32 tiles)
#define SMS 66    // f32 stride of message tile

__device__ __forceinline__ u16 f2bf(float f) {
  unsigned int u = __builtin_bit_cast(unsigned int, f);
  u += 0x7fffu + ((u >> 16) & 1u);
  return (u16)(u >> 16);
}
__device__ __forceinline__ float bf2f(u16 h) {
  unsigned int u = ((unsigned int)h) << 16;
  return __builtin_bit_cast(float, u);
}
__device__ __forceinline__ void split8(const f32x4 a0, const f32x4 a1,
                                       bf16x8& hi, bf16x8& lo) {
  u16x8 h_, l_;
#pragma unroll
  for (int j = 0; j < 4; ++j) {
    float v = a0[j]; u16 hb = f2bf(v); h_[j] = hb; l_[j] = f2bf(v - bf2f(hb));
    v = a1[j]; hb = f2bf(v); h_[4 + j] = hb; l_[4 + j] = f2bf(v - bf2f(hb));
  }
  hi = __builtin_bit_cast(bf16x8, h_);
  lo = __builtin_bit_cast(bf16x8, l_);
}

// ---------------------------------------------------------------- setup ----
// frag(kk,nt,lane,j) = W[kk*32 + (lane>>4)*8 + j][nt*16 + (lane&15)]
__global__ __launch_bounds__(256)
void setup_kernel(const float* __restrict__ node_W, const float* __restrict__ edge_W,
                  const float* __restrict__ edge_b, const float* __restrict__ W1,
                  const float* __restrict__ b1, const float* __restrict__ W2,
                  const float* __restrict__ fin_W1,
                  u16* __restrict__ nWf, u16* __restrict__ W1T, u16* __restrict__ W1E,
                  u16* __restrict__ W2f, u16* __restrict__ fWs, u16* __restrict__ fWd,
                  float* __restrict__ b1p)
{
  const int tid = threadIdx.x;
  const int blk = blockIdx.x;
  if (blk == 0) {
    for (int idx = tid; idx < 8192; idx += 256) {
      int j = idx & 7, l = (idx >> 3) & 63, nt = (idx >> 9) & 3, kk = idx >> 11;
      int k = kk * 32 + (l >> 4) * 8 + j, n = nt * 16 + (l & 15);
      nWf[idx] = f2bf(node_W[k * HH + n]);
    }
  } else if (blk == 5) {
    for (int idx = tid; idx < 4096; idx += 256) {
      int j = idx & 7, l = (idx >> 3) & 63, nt = (idx >> 9) & 3, kk = idx >> 11;
      int k = kk * 32 + (l >> 4) * 8 + j, n = nt * 16 + (l & 15);
      fWs[idx] = f2bf(fin_W1[k * HH + n]);
      fWd[idx] = f2bf(fin_W1[(k + 64) * HH + n]);
    }
  } else {
    const int layer = blk - 1;
    __shared__ float e1[32 * 64];
    const float* W1l = W1 + (size_t)layer * NDIM * HH;
    for (int idx = tid; idx < 2048; idx += 256) {
      int a = idx >> 6, n = idx & 63;
      float s = 0.f;
      for (int k = 0; k < 64; ++k) s += edge_W[a * HH + k] * W1l[(64 + k) * HH + n];
      e1[a * 64 + n] = s;
    }
    if (tid < 64) {
      float s = b1[layer * HH + tid];
      for (int k = 0; k < 64; ++k) s += edge_b[k] * W1l[(64 + k) * HH + tid];
      b1p[layer * HH + tid] = s;
    }
    __syncthreads();
    for (int idx = tid; idx < 4096; idx += 256) {
      int j = idx & 7, l = (idx >> 3) & 63, nt = (idx >> 9) & 3, kk = idx >> 11;
      int k = kk * 32 + (l >> 4) * 8 + j, n = nt * 16 + (l & 15);
      W1T[layer * 4096 + idx] = f2bf(W1l[k * HH + n]);
    }
    for (int idx = tid; idx < 2048; idx += 256) {
      int j = idx & 7, l = (idx >> 3) & 63, nt = idx >> 9;
      int k = (l >> 4) * 8 + j, n = nt * 16 + (l & 15);
      W1E[layer * 2048 + idx] = f2bf(e1[k * 64 + n]);
    }
    for (int idx = tid; idx < 4096; idx += 256) {
      int j = idx & 7, l = (idx >> 3) & 63, nt = (idx >> 9) & 3, kk = idx >> 11;
      int k = kk * 32 + (l >> 4) * 8 + j, n = nt * 16 + (l & 15);
      W2f[layer * 4096 + idx] = f2bf(W2[((size_t)layer * HH + k) * HH + n]);
    }
  }
}

// ------------------------------------------------------- counting sort -----
__global__ __launch_bounds__(256)
void zero2(int* __restrict__ cnt, float* __restrict__ h32)
{
  int t = blockIdx.x * 256 + threadIdx.x;
  if (t < 50176) cnt[t] = 0;
  if (t < EE) {
    f32x4 z = (f32x4){0.f, 0.f, 0.f, 0.f};
    *reinterpret_cast<f32x4*>(h32 + (size_t)t * 4) = z;
  }
}

__global__ __launch_bounds__(256)
void hist_kernel(const int* __restrict__ ei, int* __restrict__ cnt)
{
  int e = blockIdx.x * 256 + threadIdx.x;
  if (e < EE) atomicAdd(&cnt[ei[EE + e]], 1);
}

__global__ __launch_bounds__(256)
void chunk_sum(const int* __restrict__ cnt, int* __restrict__ bsum)
{
  int i = blockIdx.x * 256 + threadIdx.x;
  int v = (i < NN) ? cnt[i] : 0;
  int lane = threadIdx.x & 63, wv = threadIdx.x >> 6;
#pragma unroll
  for (int m = 1; m < 64; m <<= 1) v += __shfl_xor(v, m, 64);
  __shared__ int ws4[4];
  if (lane == 0) ws4[wv] = v;
  __syncthreads();
  if (threadIdx.x == 0) bsum[blockIdx.x] = ws4[0] + ws4[1] + ws4[2] + ws4[3];
}

__global__ __launch_bounds__(64)
void scan_small(int* __restrict__ bsum)
{
  int lane = threadIdx.x;
  int carry = 0;
  for (int r = 0; r < (NBLK + 63) / 64; ++r) {
    int idx = r * 64 + lane;
    int v = (idx < NBLK) ? bsum[idx] : 0;
    int s = v;
#pragma unroll
    for (int d = 1; d < 64; d <<= 1) {
      int t = __shfl_up(s, d, 64);
      if (lane >= d) s += t;
    }
    if (idx < NBLK) bsum[idx] = s - v + carry;
    carry += __shfl(s, 63, 64);
  }
}

__global__ __launch_bounds__(256)
void scan_write(int* __restrict__ cursor, const int* __restrict__ bsum,
                float* __restrict__ degf)
{
  int i = blockIdx.x * 256 + threadIdx.x;
  int v = (i < NN) ? cursor[i] : 0;
  int lane = threadIdx.x & 63, wv = threadIdx.x >> 6;
  int s = v;
#pragma unroll
  for (int d = 1; d < 64; d <<= 1) {
    int t = __shfl_up(s, d, 64);
    if (lane >= d) s += t;
  }
  __shared__ int ws4[4];
  if (lane == 63) ws4[wv] = s;
  __syncthreads();
  int wo = 0;
  for (int w = 0; w < wv; ++w) wo += ws4[w];
  if (i < NN) {
    cursor[i] = s - v + wo + bsum[blockIdx.x];
    degf[i] = (float)v;
  }
}

// scatter_pay: coalesced ei + edge_attr reads; normal (L2-cached) random
// writes of packed (src,dst) and the bf16 ea row to the sorted position.
// (NT stores measured 2x WORSE here — L2 merges adjacent-position writes.)
__global__ __launch_bounds__(256)
void scatter_pay(const int* __restrict__ ei, const float* __restrict__ edge_attr,
                 int* __restrict__ cursor, u32* __restrict__ sd, u16* __restrict__ eap)
{
  int e = blockIdx.x * 256 + threadIdx.x;
  if (e >= EE) return;
  int s = ei[e];
  int d = ei[EE + e];
  const f32x4* pa = reinterpret_cast<const f32x4*>(edge_attr + (size_t)e * EDIM);
  f32x4 v[8];
#pragma unroll
  for (int q = 0; q < 8; ++q) v[q] = pa[q];
  u16x8 o[4];
#pragma unroll
  for (int q = 0; q < 4; ++q)
#pragma unroll
    for (int j = 0; j < 4; ++j) {
      o[q][j] = f2bf(v[2 * q][j]);
      o[q][4 + j] = f2bf(v[2 * q + 1][j]);
    }
  int pos = atomicAdd(&cursor[d], 1);
  sd[pos] = ((u32)s << 16) | (u32)d;
  u16* po = eap + (size_t)pos * EDIM;
#pragma unroll
  for (int q = 0; q < 4; ++q)
    *reinterpret_cast<u16x8*>(po + q * 8) = o[q];
}

// ------------------------------- node enc: h0 (f32) -> p0 (split GEMM) -----
// p storage is PERMUTED: p[node*64 + r16*4 + nt] == logical col nt*16+r16.
__global__ __launch_bounds__(256, 2)
void node_enc(const float* __restrict__ x, const u16* __restrict__ nWf,
              const float* __restrict__ node_b, const u16* __restrict__ W1T,
              float* __restrict__ p)
{
  __shared__ __align__(16) char ebuf[64 * 272];   // Xs (u16 LDX) / Hs (f32 LHS)
  u16* Xs = reinterpret_cast<u16*>(ebuf);
  float* Hs = reinterpret_cast<float*>(ebuf);
  const int tid = threadIdx.x;
  const int base = blockIdx.x * 64;
  const int lane = tid & 63, wv = tid >> 6;
  const int r16 = lane & 15, kg = lane >> 4;

  bf16x8 Bf[4][4];
#pragma unroll
  for (int kk = 0; kk < 4; ++kk)
#pragma unroll
    for (int nt = 0; nt < 4; ++nt)
      Bf[kk][nt] = *reinterpret_cast<const bf16x8*>(nWf + ((kk * 4 + nt) * 64 + lane) * 8);
  float bias[4];
#pragma unroll
  for (int nt = 0; nt < 4; ++nt) bias[nt] = node_b[nt * 16 + r16];

#pragma unroll
  for (int it = 0; it < 4; ++it) {
    int s = it * 256 + tid;
    int r = s >> 4, c = (s & 15) * 8;
    int node = base + r;
    u16x8 o;
    if (node < NN) {
      const f32x4* px = reinterpret_cast<const f32x4*>(x + (size_t)node * NDIM + c);
      f32x4 v0 = px[0], v1 = px[1];
#pragma unroll
      for (int j = 0; j < 4; ++j) { o[j] = f2bf(v0[j]); o[4 + j] = f2bf(v1[j]); }
    } else {
#pragma unroll
      for (int j = 0; j < 8; ++j) o[j] = 0;
    }
    *reinterpret_cast<u16x8*>(&Xs[r * LDX + c]) = o;
  }
  __syncthreads();

  f32x4 acc[4];
#pragma unroll
  for (int nt = 0; nt < 4; ++nt) acc[nt] = (f32x4){0.f, 0.f, 0.f, 0.f};
#pragma unroll
  for (int kk = 0; kk < 4; ++kk) {
    bf16x8 a = *reinterpret_cast<const bf16x8*>(&Xs[(wv * 16 + r16) * LDX + kk * 32 + kg * 8]);
#pragma unroll
    for (int nt = 0; nt < 4; ++nt)
      acc[nt] = __builtin_amdgcn_mfma_f32_16x16x32_bf16(a, Bf[kk][nt], acc[nt], 0, 0, 0);
  }
  __syncthreads();

#pragma unroll
  for (int nt = 0; nt < 4; ++nt)
#pragma unroll
    for (int j = 0; j < 4; ++j)
      Hs[(wv * 16 + kg * 4 + j) * LHS + nt * 16 + r16] = acc[nt][j] + bias[nt];
  __syncthreads();

  bf16x8 Bt[2][4];
#pragma unroll
  for (int kk = 0; kk < 2; ++kk)
#pragma unroll
    for (int nt = 0; nt < 4; ++nt)
      Bt[kk][nt] = *reinterpret_cast<const bf16x8*>(W1T + ((kk * 4 + nt) * 64 + lane) * 8);

  f32x4 acc2[4];
#pragma unroll
  for (int nt = 0; nt < 4; ++nt) acc2[nt] = (f32x4){0.f, 0.f, 0.f, 0.f};
#pragma unroll
  for (int kk = 0; kk < 2; ++kk) {
    const f32x4* pa = reinterpret_cast<const f32x4*>(&Hs[(wv * 16 + r16) * LHS + kk * 32 + kg * 8]);
    f32x4 a0 = pa[0], a1 = pa[1];
    bf16x8 hi, lo;
    split8(a0, a1, hi, lo);
#pragma unroll
    for (int nt = 0; nt < 4; ++nt) {
      acc2[nt] = __builtin_amdgcn_mfma_f32_16x16x32_bf16(hi, Bt[kk][nt], acc2[nt], 0, 0, 0);
      acc2[nt] = __builtin_amdgcn_mfma_f32_16x16x32_bf16(lo, Bt[kk][nt], acc2[nt], 0, 0, 0);
    }
  }
#pragma unroll
  for (int j = 0; j < 4; ++j) {
    int node = base + wv * 16 + kg * 4 + j;
    if (node < NN) {
      f32x4 w;
#pragma unroll
      for (int nt = 0; nt < 4; ++nt) w[nt] = acc2[nt][j];
      *reinterpret_cast<f32x4*>(p + (size_t)node * HH + r16 * 4) = w;
    }
  }
}

// --------------------- message: relu(p_src+p_dst+ea@W1e'+b1'), aggregate ---
__global__ __launch_bounds__(256, 8)
void msg2(const u32* __restrict__ sd, const u16* __restrict__ eap,
          const float* __restrict__ p, float* __restrict__ h32,
          const u16* __restrict__ W1E, const float* __restrict__ b1p, int layer)
{
  __shared__ float Sm[64 * SMS];
  __shared__ u32 sd_s[64];
  __shared__ int segpos[64];
  __shared__ int segn;

  const int tid = threadIdx.x;
  const int base = blockIdx.x * 64;
  const int lane = tid & 63, wv = tid >> 6;
  const int r16 = lane & 15, kg = lane >> 4;

  if (tid < 64) sd_s[tid] = sd[base + tid];

  bf16x8 B1[4];
  const u16* w1 = W1E + layer * 2048;
#pragma unroll
  for (int nt = 0; nt < 4; ++nt)
    B1[nt] = *reinterpret_cast<const bf16x8*>(w1 + (nt * 64 + lane) * 8);
  float b1v[4];
#pragma unroll
  for (int nt = 0; nt < 4; ++nt) b1v[nt] = b1p[layer * HH + nt * 16 + r16];

  // A-frag: pre-sorted bf16 edge_attr, direct 16B streaming load
  bf16x8 af = *reinterpret_cast<const bf16x8*>(
      eap + (size_t)(base + wv * 16 + r16) * EDIM + kg * 8);
  __syncthreads();

  if (wv == 0) {
    int dme = sd_s[lane] & 0xffff;
    int dpr = (lane > 0) ? (sd_s[lane - 1] & 0xffff) : -1;
    bool st = (dme != dpr);
    unsigned long long m = __ballot(st);
    if (st) {
      int rk = __popcll(m & ((1ull << lane) - 1ull));
      segpos[rk] = lane;
    }
    if (lane == 0) segn = __popcll(m);
  }

  // C init: p[src]+p[dst]+b1' via permuted-layout float4 gathers
  f32x4 acc[4];
#pragma unroll
  for (int j = 0; j < 4; ++j) {
    int row = wv * 16 + kg * 4 + j;
    u32 w = sd_s[row];
    const f32x4 a = *reinterpret_cast<const f32x4*>(p + (size_t)(w >> 16) * HH + r16 * 4);
    const f32x4 b = *reinterpret_cast<const f32x4*>(p + (size_t)(w & 0xffff) * HH + r16 * 4);
#pragma unroll
    for (int nt = 0; nt < 4; ++nt) acc[nt][j] = a[nt] + b[nt] + b1v[nt];
  }

#pragma unroll
  for (int nt = 0; nt < 4; ++nt)
    acc[nt] = __builtin_amdgcn_mfma_f32_16x16x32_bf16(af, B1[nt], acc[nt], 0, 0, 0);

#pragma unroll
  for (int nt = 0; nt < 4; ++nt)
#pragma unroll
    for (int j = 0; j < 4; ++j)
      Sm[(wv * 16 + kg * 4 + j) * SMS + nt * 16 + r16] = fmaxf(acc[nt][j], 0.f);
  __syncthreads();

  int ns = segn;
  for (int s = wv; s < ns; s += 4) {
    int r0 = segpos[s];
    int r1 = (s + 1 < ns) ? segpos[s + 1] : 64;
    float sum = 0.f;
    for (int r = r0; r < r1; ++r) sum += Sm[r * SMS + lane];
    unsafeAtomicAdd(&h32[(size_t)(sd_s[r0] & 0xffff) * HH + lane], sum);
  }
}

// ------ node update: h = hsum@W2 + deg*b2 (split); p' = h@W1top' (split);
// ------ on layer 3: r_src = h@fin_W1_top, r_dst = h@fin_W1_bot + fin_b1 ----
__global__ __launch_bounds__(256, 2)
void node_update(float* __restrict__ h32, const float* __restrict__ degf,
                 const u16* __restrict__ W2f, const float* __restrict__ b2a,
                 const u16* __restrict__ W1T, float* __restrict__ p,
                 const u16* __restrict__ fWs, const u16* __restrict__ fWd,
                 const float* __restrict__ fin_b1,
                 u16* __restrict__ r_src, u16* __restrict__ r_dst, int layer)
{
  __shared__ __align__(16) float Hs[64 * LHS];
  const int tid = threadIdx.x;
  const int base = blockIdx.x * 64;
  const int lane = tid & 63, wv = tid >> 6;
  const int r16 = lane & 15, kg = lane >> 4;

#pragma unroll
  for (int it = 0; it < 2; ++it) {
    int s = it * 256 + tid;
    int r = s >> 3, c = (s & 7) * 8;
    int node = base + r;
    f32x4 v0 = (f32x4){0.f, 0.f, 0.f, 0.f}, v1 = v0;
    if (node < NN) {
      f32x4* ph = reinterpret_cast<f32x4*>(h32 + (size_t)node * HH + c);
      v0 = ph[0]; v1 = ph[1];
      f32x4 z = (f32x4){0.f, 0.f, 0.f, 0.f};
      ph[0] = z; ph[1] = z;
    }
    *reinterpret_cast<f32x4*>(&Hs[r * LHS + c]) = v0;
    *reinterpret_cast<f32x4*>(&Hs[r * LHS + c + 4]) = v1;
  }

  bf16x8 B2[2][4];
  const u16* w2 = W2f + layer * 4096;
#pragma unroll
  for (int kk = 0; kk < 2; ++kk)
#pragma unroll
    for (int nt = 0; nt < 4; ++nt)
      B2[kk][nt] = *reinterpret_cast<const bf16x8*>(w2 + ((kk * 4 + nt) * 64 + lane) * 8);
  float b2v[4];
#pragma unroll
  for (int nt = 0; nt < 4; ++nt) b2v[nt] = b2a[layer * HH + nt * 16 + r16];
  float degj[4];
#pragma unroll
  for (int j = 0; j < 4; ++j) {
    int node = base + wv * 16 + kg * 4 + j;
    degj[j] = (node < NN) ? degf[node] : 0.f;
  }
  __syncthreads();

  // h = hsum @ W2 + deg*b2, split-precision A
  f32x4 acc[4];
#pragma unroll
  for (int nt = 0; nt < 4; ++nt)
#pragma unroll
    for (int j = 0; j < 4; ++j) acc[nt][j] = degj[j] * b2v[nt];
#pragma unroll
  for (int kk = 0; kk < 2; ++kk) {
    const f32x4* pa = reinterpret_cast<const f32x4*>(&Hs[(wv * 16 + r16) * LHS + kk * 32 + kg * 8]);
    f32x4 a0 = pa[0], a1 = pa[1];
    bf16x8 hi, lo;
    split8(a0, a1, hi, lo);
#pragma unroll
    for (int nt = 0; nt < 4; ++nt) {
      acc[nt] = __builtin_amdgcn_mfma_f32_16x16x32_bf16(hi, B2[kk][nt], acc[nt], 0, 0, 0);
      acc[nt] = __builtin_amdgcn_mfma_f32_16x16x32_bf16(lo, B2[kk][nt], acc[nt], 0, 0, 0);
    }
  }

  __syncthreads();
#pragma unroll
  for (int nt = 0; nt < 4; ++nt)
#pragma unroll
    for (int j = 0; j < 4; ++j)
      Hs[(wv * 16 + kg * 4 + j) * LHS + nt * 16 + r16] = acc[nt][j];
  __syncthreads();

  if (layer == 3) {
    bf16x8 Bs[2][4], Bd[2][4];
#pragma unroll
    for (int kk = 0; kk < 2; ++kk)
#pragma unroll
      for (int nt = 0; nt < 4; ++nt) {
        Bs[kk][nt] = *reinterpret_cast<const bf16x8*>(fWs + ((kk * 4 + nt) * 64 + lane) * 8);
        Bd[kk][nt] = *reinterpret_cast<const bf16x8*>(fWd + ((kk * 4 + nt) * 64 + lane) * 8);
      }
    float fb1v[4];
#pragma unroll
    for (int nt = 0; nt < 4; ++nt) fb1v[nt] = fin_b1[nt * 16 + r16];

    f32x4 as_[4], ad_[4];
#pragma unroll
    for (int nt = 0; nt < 4; ++nt) {
      as_[nt] = (f32x4){0.f, 0.f, 0.f, 0.f};
#pragma unroll
      for (int j = 0; j < 4; ++j) ad_[nt][j] = fb1v[nt];
    }
#pragma unroll
    for (int kk = 0; kk < 2; ++kk) {
      const f32x4* pa = reinterpret_cast<const f32x4*>(&Hs[(wv * 16 + r16) * LHS + kk * 32 + kg * 8]);
      f32x4 a0 = pa[0], a1 = pa[1];
      bf16x8 hi, lo;
      split8(a0, a1, hi, lo);
#pragma unroll
      for (int nt = 0; nt < 4; ++nt) {
        as_[nt] = __builtin_amdgcn_mfma_f32_16x16x32_bf16(hi, Bs[kk][nt], as_[nt], 0, 0, 0);
        as_[nt] = __builtin_amdgcn_mfma_f32_16x16x32_bf16(lo, Bs[kk][nt], as_[nt], 0, 0, 0);
        ad_[nt] = __builtin_amdgcn_mfma_f32_16x16x32_bf16(hi, Bd[kk][nt], ad_[nt], 0, 0, 0);
        ad_[nt] = __builtin_amdgcn_mfma_f32_16x16x32_bf16(lo, Bd[kk][nt], ad_[nt], 0, 0, 0);
      }
    }
#pragma unroll
    for (int j = 0; j < 4; ++j) {
      int node = base + wv * 16 + kg * 4 + j;
      if (node < NN) {
#pragma unroll
        for (int nt = 0; nt < 4; ++nt) {
          r_src[(size_t)node * HH + nt * 16 + r16] = f2bf(as_[nt][j]);
          r_dst[(size_t)node * HH + nt * 16 + r16] = f2bf(ad_[nt][j]);
        }
      }
    }
    return;
  }

  // p' = h @ W1top[layer+1] (split)
  bf16x8 Bt[2][4];
  const u16* wt = W1T + (layer + 1) * 4096;
#pragma unroll
  for (int kk = 0; kk < 2; ++kk)
#pragma unroll
    for (int nt = 0; nt < 4; ++nt)
      Bt[kk][nt] = *reinterpret_cast<const bf16x8*>(wt + ((kk * 4 + nt) * 64 + lane) * 8);

  f32x4 acc2[4];
#pragma unroll
  for (int nt = 0; nt < 4; ++nt) acc2[nt] = (f32x4){0.f, 0.f, 0.f, 0.f};
#pragma unroll
  for (int kk = 0; kk < 2; ++kk) {
    const f32x4* pa = reinterpret_cast<const f32x4*>(&Hs[(wv * 16 + r16) * LHS + kk * 32 + kg * 8]);
    f32x4 a0 = pa[0], a1 = pa[1];
    bf16x8 hi, lo;
    split8(a0, a1, hi, lo);
#pragma unroll
    for (int nt = 0; nt < 4; ++nt) {
      acc2[nt] = __builtin_amdgcn_mfma_f32_16x16x32_bf16(hi, Bt[kk][nt], acc2[nt], 0, 0, 0);
      acc2[nt] = __builtin_amdgcn_mfma_f32_16x16x32_bf16(lo, Bt[kk][nt], acc2[nt], 0, 0, 0);
    }
  }
#pragma unroll
  for (int j = 0; j < 4; ++j) {
    int node = base + wv * 16 + kg * 4 + j;
    if (node < NN) {
      f32x4 w;
#pragma unroll
      for (int nt = 0; nt < 4; ++nt) w[nt] = acc2[nt][j];
      *reinterpret_cast<f32x4*>(p + (size_t)node * HH + r16 * 4) = w;
    }
  }
}

// -- final: 4 threads/edge, original order; coalesced 128B row-gathers ------
__global__ __launch_bounds__(256)
void final2(const int* __restrict__ ei, const u16* __restrict__ r_src,
            const u16* __restrict__ r_dst, const float* __restrict__ fin_W2,
            const float* __restrict__ fin_b2, float* __restrict__ out)
{
  __shared__ float w2s[64];
  const int tid = threadIdx.x;
  if (tid < 64) w2s[tid] = fin_W2[tid];
  __syncthreads();
  int t = blockIdx.x * 256 + tid;
  int e = t >> 2, q = t & 3;            // 4 threads per edge, 16 cols each
  if (e >= EE) return;
  int s = ei[e], d = ei[EE + e];
  const u16x8* prs = reinterpret_cast<const u16x8*>(r_src + (size_t)s * HH + q * 16);
  const u16x8* prd = reinterpret_cast<const u16x8*>(r_dst + (size_t)d * HH + q * 16);
  float acc = 0.f;
#pragma unroll
  for (int h = 0; h < 2; ++h) {
    u16x8 a = prs[h], b = prd[h];
#pragma unroll
    for (int j = 0; j < 8; ++j) {
      float v = bf2f(a[j]) + bf2f(b[j]);
      acc += fmaxf(v, 0.f) * w2s[q * 16 + h * 8 + j];
    }
  }
  acc += __shfl_xor(acc, 1, 64);
  acc += __shfl_xor(acc, 2, 64);
  if (q == 0) out[e] = acc + fin_b2[0];
}

// ---------------------------------------------------------------- launch ---
extern "C" void kernel_launch(void* const* d_in, const int* in_sizes, int n_in,
                              void* d_out, int out_size, void* d_ws, size_t ws_size,
                              hipStream_t stream)
{
  const float* x      = (const float*)d_in[0];
  const float* eattr  = (const float*)d_in[1];
  const int*   ei     = (const int*)d_in[2];
  const float* node_W = (const float*)d_in[3];
  const float* node_b = (const float*)d_in[4];
  const float* edge_W = (const float*)d_in[5];
  const float* edge_b = (const float*)d_in[6];
  const float* W1     = (const float*)d_in[7];
  const float* b1     = (const float*)d_in[8];
  const float* W2     = (const float*)d_in[9];
  const float* b2     = (const float*)d_in[10];
  const float* fin_W1 = (const float*)d_in[11];
  const float* fin_b1 = (const float*)d_in[12];
  const float* fin_W2 = (const float*)d_in[13];
  const float* fin_b2 = (const float*)d_in[14];

  char* ws    = (char*)d_ws;
  float* h32  = (float*)(ws + OFF_H32);
  float* p    = (float*)(ws + OFF_P);
  u16* r_src  = (u16*)(ws + OFF_RS);
  u16* r_dst  = (u16*)(ws + OFF_RD);
  u16* nWf    = (u16*)(ws + OFF_NWF);
  u16* W1T    = (u16*)(ws + OFF_W1T);
  u16* W1E    = (u16*)(ws + OFF_W1E);
  u16* W2f    = (u16*)(ws + OFF_W2F);
  u16* fWs    = (u16*)(ws + OFF_FWS);
  u16* fWd    = (u16*)(ws + OFF_FWD);
  float* b1p  = (float*)(ws + OFF_B1P);
  int* cursor = (int*)(ws + OFF_CUR);
  float* degf = (float*)(ws + OFF_DEG);
  int* bsum   = (int*)(ws + OFF_BSUM);
  u32* sd     = (u32*)(ws + OFF_SD);
  u16* eap    = (u16*)(ws + OFF_EAP);

  zero2<<<(EE + 255) / 256, 256, 0, stream>>>(cursor, h32);
  setup_kernel<<<6, 256, 0, stream>>>(node_W, edge_W, edge_b, W1, b1, W2, fin_W1,
                                      nWf, W1T, W1E, W2f, fWs, fWd, b1p);
  node_enc<<<NB64, 256, 0, stream>>>(x, nWf, node_b, W1T, p);

  hist_kernel<<<(EE + 255) / 256, 256, 0, stream>>>(ei, cursor);
  chunk_sum<<<NBLK, 256, 0, stream>>>(cursor, bsum);
  scan_small<<<1, 64, 0, stream>>>(bsum);
  scan_write<<<NBLK, 256, 0, stream>>>(cursor, bsum, degf);
  scatter_pay<<<(EE + 255) / 256, 256, 0, stream>>>(ei, eattr, cursor, sd, eap);

  for (int l = 0; l < 4; ++l) {
    msg2<<<EE / 64, 256, 0, stream>>>(sd, eap, p, h32, W1E, b1p, l);
    node_update<<<NB64, 256, 0, stream>>>(h32, degf, W2f, b2, W1T, p,
                                          fWs, fWd, fin_b1, r_src, r_dst, l);
  }
  final2<<<(EE * 4 + 255) / 256, 256, 0, stream>>>(ei, r_src, r_dst,
                                                   fin_W2, fin_b2, (float*)d_out);
}

// Round 17
// 308.367 us; speedup vs baseline: 1.2539x; 1.1174x over previous
//
#include <hip/hip_runtime.h>

#define NN 50000
#define EE 800000
#define NDIM 128
#define EDIM 32
#define HH 64
#define NBLK 196        // ceil(NN/256)
#define NB64 782        // ceil(NN/64)

typedef unsigned short u16;
typedef unsigned int u32;
typedef u16 u16x4 __attribute__((ext_vector_type(4)));
typedef u16 u16x8 __attribute__((ext_vector_type(8)));
typedef __bf16 bf16x8 __attribute__((ext_vector_type(8)));
typedef float f32x4 __attribute__((ext_vector_type(4)));

// ws layout (bytes) — ws = 400 MB confirmed by poison fill
#define OFF_H32  0ull                        // NN*HH f32 hsum accumulator
#define OFF_P    12800000ull                 // NN*HH u16 (bf16!), PERMUTED [node][r16*4+nt]
#define OFF_RS   25600000ull                 // NN*HH u16: r_src = h@fin_W1_top
#define OFF_RD   32000000ull                 // NN*HH u16: r_dst = h@fin_W1_bot + fin_b1
#define OFF_NWF  38400000ull                 // 16,384
#define OFF_W1T  (OFF_NWF + 16384ull)        // 32,768
#define OFF_W1E  (OFF_W1T + 32768ull)        // 16,384
#define OFF_W2F  (OFF_W1E + 16384ull)        // 32,768
#define OFF_FWS  (OFF_W2F + 32768ull)        // 8,192
#define OFF_FWD  (OFF_FWS + 8192ull)         // 8,192
#define OFF_B1P  (OFF_FWD + 8192ull)         // 1,024
#define OFF_CUR  (OFF_B1P + 1024ull)         // 200,704
#define OFF_DEG  (OFF_CUR + 200704ull)       // 200,704
#define OFF_BSUM (OFF_DEG + 200704ull)       // 1,024
#define OFF_SD   (OFF_BSUM + 1024ull)        // EE*4 (packed src<<16|dst, sorted)
#define OFF_EAP  (OFF_SD + 3200000ull)       // EE*32*2 = 51,200,000 (bf16, sorted)
#define WS_NEED  (OFF_EAP + 51200000ull)

#define LDX 136   // u16 stride (node_enc X tile)
#define LHS 68    // f32 stride (node-level f32 tiles)
#define SMS 66    // f32 stride of message tile

__device__ __forceinline__ u16 f2bf(float f) {
  unsigned int u = __builtin_bit_cast(unsigned int, f);
  u += 0x7fffu + ((u >> 16) & 1u);
  return (u16)(u >> 16);
}
__device__ __forceinline__ float bf2f(u16 h) {
  unsigned int u = ((unsigned int)h) << 16;
  return __builtin_bit_cast(float, u);
}
__device__ __forceinline__ void split8(const f32x4 a0, const f32x4 a1,
                                       bf16x8& hi, bf16x8& lo) {
  u16x8 h_, l_;
#pragma unroll
  for (int j = 0; j < 4; ++j) {
    float v = a0[j]; u16 hb = f2bf(v); h_[j] = hb; l_[j] = f2bf(v - bf2f(hb));
    v = a1[j]; hb = f2bf(v); h_[4 + j] = hb; l_[4 + j] = f2bf(v - bf2f(hb));
  }
  hi = __builtin_bit_cast(bf16x8, h_);
  lo = __builtin_bit_cast(bf16x8, l_);
}

// ---------------------------------------------------------------- setup ----
// frag(kk,nt,lane,j) = W[kk*32 + (lane>>4)*8 + j][nt*16 + (lane&15)]
__global__ __launch_bounds__(256)
void setup_kernel(const float* __restrict__ node_W, const float* __restrict__ edge_W,
                  const float* __restrict__ edge_b, const float* __restrict__ W1,
                  const float* __restrict__ b1, const float* __restrict__ W2,
                  const float* __restrict__ fin_W1,
                  u16* __restrict__ nWf, u16* __restrict__ W1T, u16* __restrict__ W1E,
                  u16* __restrict__ W2f, u16* __restrict__ fWs, u16* __restrict__ fWd,
                  float* __restrict__ b1p)
{
  const int tid = threadIdx.x;
  const int blk = blockIdx.x;
  if (blk == 0) {
    for (int idx = tid; idx < 8192; idx += 256) {
      int j = idx & 7, l = (idx >> 3) & 63, nt = (idx >> 9) & 3, kk = idx >> 11;
      int k = kk * 32 + (l >> 4) * 8 + j, n = nt * 16 + (l & 15);
      nWf[idx] = f2bf(node_W[k * HH + n]);
    }
  } else if (blk == 5) {
    for (int idx = tid; idx < 4096; idx += 256) {
      int j = idx & 7, l = (idx >> 3) & 63, nt = (idx >> 9) & 3, kk = idx >> 11;
      int k = kk * 32 + (l >> 4) * 8 + j, n = nt * 16 + (l & 15);
      fWs[idx] = f2bf(fin_W1[k * HH + n]);
      fWd[idx] = f2bf(fin_W1[(k + 64) * HH + n]);
    }
  } else {
    const int layer = blk - 1;
    __shared__ float e1[32 * 64];
    const float* W1l = W1 + (size_t)layer * NDIM * HH;
    for (int idx = tid; idx < 2048; idx += 256) {
      int a = idx >> 6, n = idx & 63;
      float s = 0.f;
      for (int k = 0; k < 64; ++k) s += edge_W[a * HH + k] * W1l[(64 + k) * HH + n];
      e1[a * 64 + n] = s;
    }
    if (tid < 64) {
      float s = b1[layer * HH + tid];
      for (int k = 0; k < 64; ++k) s += edge_b[k] * W1l[(64 + k) * HH + tid];
      b1p[layer * HH + tid] = s;
    }
    __syncthreads();
    for (int idx = tid; idx < 4096; idx += 256) {
      int j = idx & 7, l = (idx >> 3) & 63, nt = (idx >> 9) & 3, kk = idx >> 11;
      int k = kk * 32 + (l >> 4) * 8 + j, n = nt * 16 + (l & 15);
      W1T[layer * 4096 + idx] = f2bf(W1l[k * HH + n]);
    }
    for (int idx = tid; idx < 2048; idx += 256) {
      int j = idx & 7, l = (idx >> 3) & 63, nt = idx >> 9;
      int k = (l >> 4) * 8 + j, n = nt * 16 + (l & 15);
      W1E[layer * 2048 + idx] = f2bf(e1[k * 64 + n]);
    }
    for (int idx = tid; idx < 4096; idx += 256) {
      int j = idx & 7, l = (idx >> 3) & 63, nt = (idx >> 9) & 3, kk = idx >> 11;
      int k = kk * 32 + (l >> 4) * 8 + j, n = nt * 16 + (l & 15);
      W2f[layer * 4096 + idx] = f2bf(W2[((size_t)layer * HH + k) * HH + n]);
    }
  }
}

// ------------------------------------------------------- counting sort -----
__global__ __launch_bounds__(256)
void zero_cursor(int* __restrict__ cnt)
{
  int i = blockIdx.x * 256 + threadIdx.x;
  if (i < 50176) cnt[i] = 0;
}

__global__ __launch_bounds__(256)
void hist_kernel(const int* __restrict__ ei, int* __restrict__ cnt)
{
  int e = blockIdx.x * 256 + threadIdx.x;
  if (e < EE) atomicAdd(&cnt[ei[EE + e]], 1);
}

__global__ __launch_bounds__(256)
void chunk_sum(const int* __restrict__ cnt, int* __restrict__ bsum)
{
  int i = blockIdx.x * 256 + threadIdx.x;
  int v = (i < NN) ? cnt[i] : 0;
  int lane = threadIdx.x & 63, wv = threadIdx.x >> 6;
#pragma unroll
  for (int m = 1; m < 64; m <<= 1) v += __shfl_xor(v, m, 64);
  __shared__ int ws4[4];
  if (lane == 0) ws4[wv] = v;
  __syncthreads();
  if (threadIdx.x == 0) bsum[blockIdx.x] = ws4[0] + ws4[1] + ws4[2] + ws4[3];
}

__global__ __launch_bounds__(64)
void scan_small(int* __restrict__ bsum)
{
  int lane = threadIdx.x;
  int carry = 0;
  for (int r = 0; r < (NBLK + 63) / 64; ++r) {
    int idx = r * 64 + lane;
    int v = (idx < NBLK) ? bsum[idx] : 0;
    int s = v;
#pragma unroll
    for (int d = 1; d < 64; d <<= 1) {
      int t = __shfl_up(s, d, 64);
      if (lane >= d) s += t;
    }
    if (idx < NBLK) bsum[idx] = s - v + carry;
    carry += __shfl(s, 63, 64);
  }
}

__global__ __launch_bounds__(256)
void scan_write(int* __restrict__ cursor, const int* __restrict__ bsum,
                float* __restrict__ degf)
{
  int i = blockIdx.x * 256 + threadIdx.x;
  int v = (i < NN) ? cursor[i] : 0;
  int lane = threadIdx.x & 63, wv = threadIdx.x >> 6;
  int s = v;
#pragma unroll
  for (int d = 1; d < 64; d <<= 1) {
    int t = __shfl_up(s, d, 64);
    if (lane >= d) s += t;
  }
  __shared__ int ws4[4];
  if (lane == 63) ws4[wv] = s;
  __syncthreads();
  int wo = 0;
  for (int w = 0; w < wv; ++w) wo += ws4[w];
  if (i < NN) {
    cursor[i] = s - v + wo + bsum[blockIdx.x];
    degf[i] = (float)v;
  }
}

// scatter_pay: coalesced ei + edge_attr reads; normal (L2-cached) random
// writes of packed (src,dst) and the bf16 ea row to the sorted position.
// Also zeroes h32 (EE threads x 16B == NN*HH f32 exactly).
__global__ __launch_bounds__(256)
void scatter_pay(const int* __restrict__ ei, const float* __restrict__ edge_attr,
                 int* __restrict__ cursor, u32* __restrict__ sd, u16* __restrict__ eap,
                 float* __restrict__ h32)
{
  int e = blockIdx.x * 256 + threadIdx.x;
  if (e >= EE) return;
  f32x4 z = (f32x4){0.f, 0.f, 0.f, 0.f};
  *reinterpret_cast<f32x4*>(h32 + (size_t)e * 4) = z;

  int s = ei[e];
  int d = ei[EE + e];
  const f32x4* pa = reinterpret_cast<const f32x4*>(edge_attr + (size_t)e * EDIM);
  f32x4 v[8];
#pragma unroll
  for (int q = 0; q < 8; ++q) v[q] = pa[q];
  u16x8 o[4];
#pragma unroll
  for (int q = 0; q < 4; ++q)
#pragma unroll
    for (int j = 0; j < 4; ++j) {
      o[q][j] = f2bf(v[2 * q][j]);
      o[q][4 + j] = f2bf(v[2 * q + 1][j]);
    }
  int pos = atomicAdd(&cursor[d], 1);
  sd[pos] = ((u32)s << 16) | (u32)d;
  u16* po = eap + (size_t)pos * EDIM;
#pragma unroll
  for (int q = 0; q < 4; ++q)
    *reinterpret_cast<u16x8*>(po + q * 8) = o[q];
}

// ------------------------------- node enc: h0 (f32) -> p0 (split GEMM) -----
// p storage is bf16, PERMUTED: p[node*64 + r16*4 + nt] == logical col nt*16+r16.
__global__ __launch_bounds__(256, 2)
void node_enc(const float* __restrict__ x, const u16* __restrict__ nWf,
              const float* __restrict__ node_b, const u16* __restrict__ W1T,
              u16* __restrict__ p)
{
  __shared__ __align__(16) char ebuf[64 * 272];   // Xs (u16 LDX) / Hs (f32 LHS)
  u16* Xs = reinterpret_cast<u16*>(ebuf);
  float* Hs = reinterpret_cast<float*>(ebuf);
  const int tid = threadIdx.x;
  const int base = blockIdx.x * 64;
  const int lane = tid & 63, wv = tid >> 6;
  const int r16 = lane & 15, kg = lane >> 4;

  bf16x8 Bf[4][4];
#pragma unroll
  for (int kk = 0; kk < 4; ++kk)
#pragma unroll
    for (int nt = 0; nt < 4; ++nt)
      Bf[kk][nt] = *reinterpret_cast<const bf16x8*>(nWf + ((kk * 4 + nt) * 64 + lane) * 8);
  float bias[4];
#pragma unroll
  for (int nt = 0; nt < 4; ++nt) bias[nt] = node_b[nt * 16 + r16];

#pragma unroll
  for (int it = 0; it < 4; ++it) {
    int s = it * 256 + tid;
    int r = s >> 4, c = (s & 15) * 8;
    int node = base + r;
    u16x8 o;
    if (node < NN) {
      const f32x4* px = reinterpret_cast<const f32x4*>(x + (size_t)node * NDIM + c);
      f32x4 v0 = px[0], v1 = px[1];
#pragma unroll
      for (int j = 0; j < 4; ++j) { o[j] = f2bf(v0[j]); o[4 + j] = f2bf(v1[j]); }
    } else {
#pragma unroll
      for (int j = 0; j < 8; ++j) o[j] = 0;
    }
    *reinterpret_cast<u16x8*>(&Xs[r * LDX + c]) = o;
  }
  __syncthreads();

  f32x4 acc[4];
#pragma unroll
  for (int nt = 0; nt < 4; ++nt) acc[nt] = (f32x4){0.f, 0.f, 0.f, 0.f};
#pragma unroll
  for (int kk = 0; kk < 4; ++kk) {
    bf16x8 a = *reinterpret_cast<const bf16x8*>(&Xs[(wv * 16 + r16) * LDX + kk * 32 + kg * 8]);
#pragma unroll
    for (int nt = 0; nt < 4; ++nt)
      acc[nt] = __builtin_amdgcn_mfma_f32_16x16x32_bf16(a, Bf[kk][nt], acc[nt], 0, 0, 0);
  }
  __syncthreads();

#pragma unroll
  for (int nt = 0; nt < 4; ++nt)
#pragma unroll
    for (int j = 0; j < 4; ++j)
      Hs[(wv * 16 + kg * 4 + j) * LHS + nt * 16 + r16] = acc[nt][j] + bias[nt];
  __syncthreads();

  bf16x8 Bt[2][4];
#pragma unroll
  for (int kk = 0; kk < 2; ++kk)
#pragma unroll
    for (int nt = 0; nt < 4; ++nt)
      Bt[kk][nt] = *reinterpret_cast<const bf16x8*>(W1T + ((kk * 4 + nt) * 64 + lane) * 8);

  f32x4 acc2[4];
#pragma unroll
  for (int nt = 0; nt < 4; ++nt) acc2[nt] = (f32x4){0.f, 0.f, 0.f, 0.f};
#pragma unroll
  for (int kk = 0; kk < 2; ++kk) {
    const f32x4* pa = reinterpret_cast<const f32x4*>(&Hs[(wv * 16 + r16) * LHS + kk * 32 + kg * 8]);
    f32x4 a0 = pa[0], a1 = pa[1];
    bf16x8 hi, lo;
    split8(a0, a1, hi, lo);
#pragma unroll
    for (int nt = 0; nt < 4; ++nt) {
      acc2[nt] = __builtin_amdgcn_mfma_f32_16x16x32_bf16(hi, Bt[kk][nt], acc2[nt], 0, 0, 0);
      acc2[nt] = __builtin_amdgcn_mfma_f32_16x16x32_bf16(lo, Bt[kk][nt], acc2[nt], 0, 0, 0);
    }
  }
#pragma unroll
  for (int j = 0; j < 4; ++j) {
    int node = base + wv * 16 + kg * 4 + j;
    if (node < NN) {
      u16x4 w4;
#pragma unroll
      for (int nt = 0; nt < 4; ++nt) w4[nt] = f2bf(acc2[nt][j]);
      *reinterpret_cast<u16x4*>(p + (size_t)node * HH + r16 * 4) = w4;
    }
  }
}

// --------------------- message: relu(p_src+p_dst+ea@W1e'+b1'), aggregate ---
__global__ __launch_bounds__(256, 8)
void msg2(const u32* __restrict__ sd, const u16* __restrict__ eap,
          const u16* __restrict__ p, float* __restrict__ h32,
          const u16* __restrict__ W1E, const float* __restrict__ b1p, int layer)
{
  __shared__ float Sm[64 * SMS];
  __shared__ u32 sd_s[64];
  __shared__ int segpos[64];
  __shared__ int segn;

  const int tid = threadIdx.x;
  const int base = blockIdx.x * 64;
  const int lane = tid & 63, wv = tid >> 6;
  const int r16 = lane & 15, kg = lane >> 4;

  if (tid < 64) sd_s[tid] = sd[base + tid];

  bf16x8 B1[4];
  const u16* w1 = W1E + layer * 2048;
#pragma unroll
  for (int nt = 0; nt < 4; ++nt)
    B1[nt] = *reinterpret_cast<const bf16x8*>(w1 + (nt * 64 + lane) * 8);
  float b1v[4];
#pragma unroll
  for (int nt = 0; nt < 4; ++nt) b1v[nt] = b1p[layer * HH + nt * 16 + r16];

  // A-frag: pre-sorted bf16 edge_attr, direct 16B streaming load
  bf16x8 af = *reinterpret_cast<const bf16x8*>(
      eap + (size_t)(base + wv * 16 + r16) * EDIM + kg * 8);
  __syncthreads();

  if (wv == 0) {
    int dme = sd_s[lane] & 0xffff;
    int dpr = (lane > 0) ? (sd_s[lane - 1] & 0xffff) : -1;
    bool st = (dme != dpr);
    unsigned long long m = __ballot(st);
    if (st) {
      int rk = __popcll(m & ((1ull << lane) - 1ull));
      segpos[rk] = lane;
    }
    if (lane == 0) segn = __popcll(m);
  }

  // C init: p[src]+p[dst]+b1' via permuted-layout bf16x4 gathers (8B each)
  f32x4 acc[4];
#pragma unroll
  for (int j = 0; j < 4; ++j) {
    int row = wv * 16 + kg * 4 + j;
    u32 w = sd_s[row];
    const u16x4 a4 = *reinterpret_cast<const u16x4*>(p + (size_t)(w >> 16) * HH + r16 * 4);
    const u16x4 b4 = *reinterpret_cast<const u16x4*>(p + (size_t)(w & 0xffff) * HH + r16 * 4);
#pragma unroll
    for (int nt = 0; nt < 4; ++nt)
      acc[nt][j] = bf2f(a4[nt]) + bf2f(b4[nt]) + b1v[nt];
  }

#pragma unroll
  for (int nt = 0; nt < 4; ++nt)
    acc[nt] = __builtin_amdgcn_mfma_f32_16x16x32_bf16(af, B1[nt], acc[nt], 0, 0, 0);

#pragma unroll
  for (int nt = 0; nt < 4; ++nt)
#pragma unroll
    for (int j = 0; j < 4; ++j)
      Sm[(wv * 16 + kg * 4 + j) * SMS + nt * 16 + r16] = fmaxf(acc[nt][j], 0.f);
  __syncthreads();

  int ns = segn;
  for (int s = wv; s < ns; s += 4) {
    int r0 = segpos[s];
    int r1 = (s + 1 < ns) ? segpos[s + 1] : 64;
    float sum = 0.f;
    for (int r = r0; r < r1; ++r) sum += Sm[r * SMS + lane];
    unsafeAtomicAdd(&h32[(size_t)(sd_s[r0] & 0xffff) * HH + lane], sum);
  }
}

// ------ node update: h = hsum@W2 + deg*b2 (split); p' = h@W1top' (split);
// ------ on layer 3: r_src = h@fin_W1_top, r_dst = h@fin_W1_bot + fin_b1 ----
__global__ __launch_bounds__(256, 3)
void node_update(float* __restrict__ h32, const float* __restrict__ degf,
                 const u16* __restrict__ W2f, const float* __restrict__ b2a,
                 const u16* __restrict__ W1T, u16* __restrict__ p,
                 const u16* __restrict__ fWs, const u16* __restrict__ fWd,
                 const float* __restrict__ fin_b1,
                 u16* __restrict__ r_src, u16* __restrict__ r_dst, int layer)
{
  __shared__ __align__(16) float Hs[64 * LHS];
  const int tid = threadIdx.x;
  const int base = blockIdx.x * 64;
  const int lane = tid & 63, wv = tid >> 6;
  const int r16 = lane & 15, kg = lane >> 4;

#pragma unroll
  for (int it = 0; it < 2; ++it) {
    int s = it * 256 + tid;
    int r = s >> 3, c = (s & 7) * 8;
    int node = base + r;
    f32x4 v0 = (f32x4){0.f, 0.f, 0.f, 0.f}, v1 = v0;
    if (node < NN) {
      f32x4* ph = reinterpret_cast<f32x4*>(h32 + (size_t)node * HH + c);
      v0 = ph[0]; v1 = ph[1];
      f32x4 z = (f32x4){0.f, 0.f, 0.f, 0.f};
      ph[0] = z; ph[1] = z;
    }
    *reinterpret_cast<f32x4*>(&Hs[r * LHS + c]) = v0;
    *reinterpret_cast<f32x4*>(&Hs[r * LHS + c + 4]) = v1;
  }

  bf16x8 B2[2][4];
  const u16* w2 = W2f + layer * 4096;
#pragma unroll
  for (int kk = 0; kk < 2; ++kk)
#pragma unroll
    for (int nt = 0; nt < 4; ++nt)
      B2[kk][nt] = *reinterpret_cast<const bf16x8*>(w2 + ((kk * 4 + nt) * 64 + lane) * 8);
  float b2v[4];
#pragma unroll
  for (int nt = 0; nt < 4; ++nt) b2v[nt] = b2a[layer * HH + nt * 16 + r16];
  float degj[4];
#pragma unroll
  for (int j = 0; j < 4; ++j) {
    int node = base + wv * 16 + kg * 4 + j;
    degj[j] = (node < NN) ? degf[node] : 0.f;
  }
  __syncthreads();

  // h = hsum @ W2 + deg*b2, split-precision A
  f32x4 acc[4];
#pragma unroll
  for (int nt = 0; nt < 4; ++nt)
#pragma unroll
    for (int j = 0; j < 4; ++j) acc[nt][j] = degj[j] * b2v[nt];
#pragma unroll
  for (int kk = 0; kk < 2; ++kk) {
    const f32x4* pa = reinterpret_cast<const f32x4*>(&Hs[(wv * 16 + r16) * LHS + kk * 32 + kg * 8]);
    f32x4 a0 = pa[0], a1 = pa[1];
    bf16x8 hi, lo;
    split8(a0, a1, hi, lo);
#pragma unroll
    for (int nt = 0; nt < 4; ++nt) {
      acc[nt] = __builtin_amdgcn_mfma_f32_16x16x32_bf16(hi, B2[kk][nt], acc[nt], 0, 0, 0);
      acc[nt] = __builtin_amdgcn_mfma_f32_16x16x32_bf16(lo, B2[kk][nt], acc[nt], 0, 0, 0);
    }
  }

  __syncthreads();
#pragma unroll
  for (int nt = 0; nt < 4; ++nt)
#pragma unroll
    for (int j = 0; j < 4; ++j)
      Hs[(wv * 16 + kg * 4 + j) * LHS + nt * 16 + r16] = acc[nt][j];
  __syncthreads();

  if (layer == 3) {
    bf16x8 Bs[2][4], Bd[2][4];
#pragma unroll
    for (int kk = 0; kk < 2; ++kk)
#pragma unroll
      for (int nt = 0; nt < 4; ++nt) {
        Bs[kk][nt] = *reinterpret_cast<const bf16x8*>(fWs + ((kk * 4 + nt) * 64 + lane) * 8);
        Bd[kk][nt] = *reinterpret_cast<const bf16x8*>(fWd + ((kk * 4 + nt) * 64 + lane) * 8);
      }
    float fb1v[4];
#pragma unroll
    for (int nt = 0; nt < 4; ++nt) fb1v[nt] = fin_b1[nt * 16 + r16];

    f32x4 as_[4], ad_[4];
#pragma unroll
    for (int nt = 0; nt < 4; ++nt) {
      as_[nt] = (f32x4){0.f, 0.f, 0.f, 0.f};
#pragma unroll
      for (int j = 0; j < 4; ++j) ad_[nt][j] = fb1v[nt];
    }
#pragma unroll
    for (int kk = 0; kk < 2; ++kk) {
      const f32x4* pa = reinterpret_cast<const f32x4*>(&Hs[(wv * 16 + r16) * LHS + kk * 32 + kg * 8]);
      f32x4 a0 = pa[0], a1 = pa[1];
      bf16x8 hi, lo;
      split8(a0, a1, hi, lo);
#pragma unroll
      for (int nt = 0; nt < 4; ++nt) {
        as_[nt] = __builtin_amdgcn_mfma_f32_16x16x32_bf16(hi, Bs[kk][nt], as_[nt], 0, 0, 0);
        as_[nt] = __builtin_amdgcn_mfma_f32_16x16x32_bf16(lo, Bs[kk][nt], as_[nt], 0, 0, 0);
        ad_[nt] = __builtin_amdgcn_mfma_f32_16x16x32_bf16(hi, Bd[kk][nt], ad_[nt], 0, 0, 0);
        ad_[nt] = __builtin_amdgcn_mfma_f32_16x16x32_bf16(lo, Bd[kk][nt], ad_[nt], 0, 0, 0);
      }
    }
#pragma unroll
    for (int j = 0; j < 4; ++j) {
      int node = base + wv * 16 + kg * 4 + j;
      if (node < NN) {
#pragma unroll
        for (int nt = 0; nt < 4; ++nt) {
          r_src[(size_t)node * HH + nt * 16 + r16] = f2bf(as_[nt][j]);
          r_dst[(size_t)node * HH + nt * 16 + r16] = f2bf(ad_[nt][j]);
        }
      }
    }
    return;
  }

  // p' = h @ W1top[layer+1] (split), stored bf16 permuted
  bf16x8 Bt[2][4];
  const u16* wt = W1T + (layer + 1) * 4096;
#pragma unroll
  for (int kk = 0; kk < 2; ++kk)
#pragma unroll
    for (int nt = 0; nt < 4; ++nt)
      Bt[kk][nt] = *reinterpret_cast<const bf16x8*>(wt + ((kk * 4 + nt) * 64 + lane) * 8);

  f32x4 acc2[4];
#pragma unroll
  for (int nt = 0; nt < 4; ++nt) acc2[nt] = (f32x4){0.f, 0.f, 0.f, 0.f};
#pragma unroll
  for (int kk = 0; kk < 2; ++kk) {
    const f32x4* pa = reinterpret_cast<const f32x4*>(&Hs[(wv * 16 + r16) * LHS + kk * 32 + kg * 8]);
    f32x4 a0 = pa[0], a1 = pa[1];
    bf16x8 hi, lo;
    split8(a0, a1, hi, lo);
#pragma unroll
    for (int nt = 0; nt < 4; ++nt) {
      acc2[nt] = __builtin_amdgcn_mfma_f32_16x16x32_bf16(hi, Bt[kk][nt], acc2[nt], 0, 0, 0);
      acc2[nt] = __builtin_amdgcn_mfma_f32_16x16x32_bf16(lo, Bt[kk][nt], acc2[nt], 0, 0, 0);
    }
  }
#pragma unroll
  for (int j = 0; j < 4; ++j) {
    int node = base + wv * 16 + kg * 4 + j;
    if (node < NN) {
      u16x4 w4;
#pragma unroll
      for (int nt = 0; nt < 4; ++nt) w4[nt] = f2bf(acc2[nt][j]);
      *reinterpret_cast<u16x4*>(p + (size_t)node * HH + r16 * 4) = w4;
    }
  }
}

// -- final: 4 threads/edge, original order; coalesced 128B row-gathers ------
__global__ __launch_bounds__(256)
void final2(const int* __restrict__ ei, const u16* __restrict__ r_src,
            const u16* __restrict__ r_dst, const float* __restrict__ fin_W2,
            const float* __restrict__ fin_b2, float* __restrict__ out)
{
  __shared__ float w2s[64];
  const int tid = threadIdx.x;
  if (tid < 64) w2s[tid] = fin_W2[tid];
  __syncthreads();
  int t = blockIdx.x * 256 + tid;
  int e = t >> 2, q = t & 3;            // 4 threads per edge, 16 cols each
  if (e >= EE) return;
  int s = ei[e], d = ei[EE + e];
  const u16x8* prs = reinterpret_cast<const u16x8*>(r_src + (size_t)s * HH + q * 16);
  const u16x8* prd = reinterpret_cast<const u16x8*>(r_dst + (size_t)d * HH + q * 16);
  float acc = 0.f;
#pragma unroll
  for (int h = 0; h < 2; ++h) {
    u16x8 a = prs[h], b = prd[h];
#pragma unroll
    for (int j = 0; j < 8; ++j) {
      float v = bf2f(a[j]) + bf2f(b[j]);
      acc += fmaxf(v, 0.f) * w2s[q * 16 + h * 8 + j];
    }
  }
  acc += __shfl_xor(acc, 1, 64);
  acc += __shfl_xor(acc, 2, 64);
  if (q == 0) out[e] = acc + fin_b2[0];
}

// ---------------------------------------------------------------- launch ---
extern "C" void kernel_launch(void* const* d_in, const int* in_sizes, int n_in,
                              void* d_out, int out_size, void* d_ws, size_t ws_size,
                              hipStream_t stream)
{
  const float* x      = (const float*)d_in[0];
  const float* eattr  = (const float*)d_in[1];
  const int*   ei     = (const int*)d_in[2];
  const float* node_W = (const float*)d_in[3];
  const float* node_b = (const float*)d_in[4];
  const float* edge_W = (const float*)d_in[5];
  const float* edge_b = (const float*)d_in[6];
  const float* W1     = (const float*)d_in[7];
  const float* b1     = (const float*)d_in[8];
  const float* W2     = (const float*)d_in[9];
  const float* b2     = (const float*)d_in[10];
  const float* fin_W1 = (const float*)d_in[11];
  const float* fin_b1 = (const float*)d_in[12];
  const float* fin_W2 = (const float*)d_in[13];
  const float* fin_b2 = (const float*)d_in[14];

  char* ws    = (char*)d_ws;
  float* h32  = (float*)(ws + OFF_H32);
  u16* p      = (u16*)(ws + OFF_P);
  u16* r_src  = (u16*)(ws + OFF_RS);
  u16* r_dst  = (u16*)(ws + OFF_RD);
  u16* nWf    = (u16*)(ws + OFF_NWF);
  u16* W1T    = (u16*)(ws + OFF_W1T);
  u16* W1E    = (u16*)(ws + OFF_W1E);
  u16* W2f    = (u16*)(ws + OFF_W2F);
  u16* fWs    = (u16*)(ws + OFF_FWS);
  u16* fWd    = (u16*)(ws + OFF_FWD);
  float* b1p  = (float*)(ws + OFF_B1P);
  int* cursor = (int*)(ws + OFF_CUR);
  float* degf = (float*)(ws + OFF_DEG);
  int* bsum   = (int*)(ws + OFF_BSUM);
  u32* sd     = (u32*)(ws + OFF_SD);
  u16* eap    = (u16*)(ws + OFF_EAP);

  zero_cursor<<<NBLK, 256, 0, stream>>>(cursor);
  setup_kernel<<<6, 256, 0, stream>>>(node_W, edge_W, edge_b, W1, b1, W2, fin_W1,
                                      nWf, W1T, W1E, W2f, fWs, fWd, b1p);
  node_enc<<<NB64, 256, 0, stream>>>(x, nWf, node_b, W1T, p);

  hist_kernel<<<(EE + 255) / 256, 256, 0, stream>>>(ei, cursor);
  chunk_sum<<<NBLK, 256, 0, stream>>>(cursor, bsum);
  scan_small<<<1, 64, 0, stream>>>(bsum);
  scan_write<<<NBLK, 256, 0, stream>>>(cursor, bsum, degf);
  scatter_pay<<<(EE + 255) / 256, 256, 0, stream>>>(ei, eattr, cursor, sd, eap, h32);

  for (int l = 0; l < 4; ++l) {
    msg2<<<EE / 64, 256, 0, stream>>>(sd, eap, p, h32, W1E, b1p, l);
    node_update<<<NB64, 256, 0, stream>>>(h32, degf, W2f, b2, W1T, p,
                                          fWs, fWd, fin_b1, r_src, r_dst, l);
  }
  final2<<<(EE * 4 + 255) / 256, 256, 0, stream>>>(ei, r_src, r_dst,
                                                   fin_W2, fin_b2, (float*)d_out);
}

// Round 20
// 305.760 us; speedup vs baseline: 1.2646x; 1.0085x over previous
//
#include <hip/hip_runtime.h>

#define NN 50000
#define EE 800000
#define NDIM 128
#define EDIM 32
#define HH 64
#define NBLK 196        // ceil(NN/256)
#define NB64 782        // ceil(NN/64)

typedef unsigned short u16;
typedef unsigned int u32;
typedef u16 u16x4 __attribute__((ext_vector_type(4)));
typedef u16 u16x8 __attribute__((ext_vector_type(8)));
typedef __bf16 bf16x8 __attribute__((ext_vector_type(8)));
typedef float f32x2 __attribute__((ext_vector_type(2)));
typedef float f32x4 __attribute__((ext_vector_type(4)));

// ws layout (bytes) — ws = 400 MB confirmed by poison fill
#define OFF_H32  0ull                        // NN*HH f32 hsum accumulator
#define OFF_P    12800000ull                 // NN*HH u16 (bf16), PERMUTED [node][r16*4+nt]
#define OFF_RS   25600000ull                 // NN*HH u16: r_src = h@fin_W1_top
#define OFF_RD   32000000ull                 // NN*HH u16: r_dst = h@fin_W1_bot + fin_b1
#define OFF_NWF  38400000ull                 // 16,384
#define OFF_W1T  (OFF_NWF + 16384ull)        // 32,768
#define OFF_W1E  (OFF_W1T + 32768ull)        // 16,384
#define OFF_W2F  (OFF_W1E + 16384ull)        // 32,768
#define OFF_FWS  (OFF_W2F + 32768ull)        // 8,192
#define OFF_FWD  (OFF_FWS + 8192ull)         // 8,192
#define OFF_B1P  (OFF_FWD + 8192ull)         // 1,024
#define OFF_CUR  (OFF_B1P + 1024ull)         // 200,704
#define OFF_DEG  (OFF_CUR + 200704ull)       // 200,704
#define OFF_BSUM (OFF_DEG + 200704ull)       // 1,024
#define OFF_SD   (OFF_BSUM + 1024ull)        // EE*4 (packed src<<16|dst, sorted)
#define OFF_EAP  (OFF_SD + 3200000ull)       // EE*32*2 = 51,200,000 (bf16, sorted)
#define WS_NEED  (OFF_EAP + 51200000ull)

#define LDX 136   // u16 stride (node_enc X tile)
#define LHS 68    // f32 stride (node-level f32 tiles)
#define SMS 66    // f32 stride of message tile

__device__ __forceinline__ u16 f2bf(float f) {
  unsigned int u = __builtin_bit_cast(unsigned int, f);
  u += 0x7fffu + ((u >> 16) & 1u);
  return (u16)(u >> 16);
}
__device__ __forceinline__ float bf2f(u16 h) {
  unsigned int u = ((unsigned int)h) << 16;
  return __builtin_bit_cast(float, u);
}
__device__ __forceinline__ void split8(const f32x4 a0, const f32x4 a1,
                                       bf16x8& hi, bf16x8& lo) {
  u16x8 h_, l_;
#pragma unroll
  for (int j = 0; j < 4; ++j) {
    float v = a0[j]; u16 hb = f2bf(v); h_[j] = hb; l_[j] = f2bf(v - bf2f(hb));
    v = a1[j]; hb = f2bf(v); h_[4 + j] = hb; l_[4 + j] = f2bf(v - bf2f(hb));
  }
  hi = __builtin_bit_cast(bf16x8, h_);
  lo = __builtin_bit_cast(bf16x8, l_);
}

// ---------------------------------------------------------------- setup ----
// frag(kk,nt,lane,j) = W[kk*32 + (lane>>4)*8 + j][nt*16 + (lane&15)]
__global__ __launch_bounds__(256)
void setup_kernel(const float* __restrict__ node_W, const float* __restrict__ edge_W,
                  const float* __restrict__ edge_b, const float* __restrict__ W1,
                  const float* __restrict__ b1, const float* __restrict__ W2,
                  const float* __restrict__ fin_W1,
                  u16* __restrict__ nWf, u16* __restrict__ W1T, u16* __restrict__ W1E,
                  u16* __restrict__ W2f, u16* __restrict__ fWs, u16* __restrict__ fWd,
                  float* __restrict__ b1p)
{
  const int tid = threadIdx.x;
  const int blk = blockIdx.x;
  if (blk == 0) {
    for (int idx = tid; idx < 8192; idx += 256) {
      int j = idx & 7, l = (idx >> 3) & 63, nt = (idx >> 9) & 3, kk = idx >> 11;
      int k = kk * 32 + (l >> 4) * 8 + j, n = nt * 16 + (l & 15);
      nWf[idx] = f2bf(node_W[k * HH + n]);
    }
  } else if (blk == 5) {
    for (int idx = tid; idx < 4096; idx += 256) {
      int j = idx & 7, l = (idx >> 3) & 63, nt = (idx >> 9) & 3, kk = idx >> 11;
      int k = kk * 32 + (l >> 4) * 8 + j, n = nt * 16 + (l & 15);
      fWs[idx] = f2bf(fin_W1[k * HH + n]);
      fWd[idx] = f2bf(fin_W1[(k + 64) * HH + n]);
    }
  } else {
    const int layer = blk - 1;
    __shared__ float e1[32 * 64];
    const float* W1l = W1 + (size_t)layer * NDIM * HH;
    for (int idx = tid; idx < 2048; idx += 256) {
      int a = idx >> 6, n = idx & 63;
      float s = 0.f;
      for (int k = 0; k < 64; ++k) s += edge_W[a * HH + k] * W1l[(64 + k) * HH + n];
      e1[a * 64 + n] = s;
    }
    if (tid < 64) {
      float s = b1[layer * HH + tid];
      for (int k = 0; k < 64; ++k) s += edge_b[k] * W1l[(64 + k) * HH + tid];
      b1p[layer * HH + tid] = s;
    }
    __syncthreads();
    for (int idx = tid; idx < 4096; idx += 256) {
      int j = idx & 7, l = (idx >> 3) & 63, nt = (idx >> 9) & 3, kk = idx >> 11;
      int k = kk * 32 + (l >> 4) * 8 + j, n = nt * 16 + (l & 15);
      W1T[layer * 4096 + idx] = f2bf(W1l[k * HH + n]);
    }
    for (int idx = tid; idx < 2048; idx += 256) {
      int j = idx & 7, l = (idx >> 3) & 63, nt = idx >> 9;
      int k = (l >> 4) * 8 + j, n = nt * 16 + (l & 15);
      W1E[layer * 2048 + idx] = f2bf(e1[k * 64 + n]);
    }
    for (int idx = tid; idx < 4096; idx += 256) {
      int j = idx & 7, l = (idx >> 3) & 63, nt = (idx >> 9) & 3, kk = idx >> 11;
      int k = kk * 32 + (l >> 4) * 8 + j, n = nt * 16 + (l & 15);
      W2f[layer * 4096 + idx] = f2bf(W2[((size_t)layer * HH + k) * HH + n]);
    }
  }
}

// ------------------------------------------------------- counting sort -----
__global__ __launch_bounds__(256)
void zero_cursor(int* __restrict__ cnt)
{
  int i = blockIdx.x * 256 + threadIdx.x;
  if (i < 50176) cnt[i] = 0;
}

__global__ __launch_bounds__(256)
void hist_kernel(const int* __restrict__ ei, int* __restrict__ cnt)
{
  int e = blockIdx.x * 256 + threadIdx.x;
  if (e < EE) atomicAdd(&cnt[ei[EE + e]], 1);
}

__global__ __launch_bounds__(256)
void chunk_sum(const int* __restrict__ cnt, int* __restrict__ bsum)
{
  int i = blockIdx.x * 256 + threadIdx.x;
  int v = (i < NN) ? cnt[i] : 0;
  int lane = threadIdx.x & 63, wv = threadIdx.x >> 6;
#pragma unroll
  for (int m = 1; m < 64; m <<= 1) v += __shfl_xor(v, m, 64);
  __shared__ int ws4[4];
  if (lane == 0) ws4[wv] = v;
  __syncthreads();
  if (threadIdx.x == 0) bsum[blockIdx.x] = ws4[0] + ws4[1] + ws4[2] + ws4[3];
}

__global__ __launch_bounds__(64)
void scan_small(int* __restrict__ bsum)
{
  int lane = threadIdx.x;
  int carry = 0;
  for (int r = 0; r < (NBLK + 63) / 64; ++r) {
    int idx = r * 64 + lane;
    int v = (idx < NBLK) ? bsum[idx] : 0;
    int s = v;
#pragma unroll
    for (int d = 1; d < 64; d <<= 1) {
      int t = __shfl_up(s, d, 64);
      if (lane >= d) s += t;
    }
    if (idx < NBLK) bsum[idx] = s - v + carry;
    carry += __shfl(s, 63, 64);
  }
}

__global__ __launch_bounds__(256)
void scan_write(int* __restrict__ cursor, const int* __restrict__ bsum,
                float* __restrict__ degf)
{
  int i = blockIdx.x * 256 + threadIdx.x;
  int v = (i < NN) ? cursor[i] : 0;
  int lane = threadIdx.x & 63, wv = threadIdx.x >> 6;
  int s = v;
#pragma unroll
  for (int d = 1; d < 64; d <<= 1) {
    int t = __shfl_up(s, d, 64);
    if (lane >= d) s += t;
  }
  __shared__ int ws4[4];
  if (lane == 63) ws4[wv] = s;
  __syncthreads();
  int wo = 0;
  for (int w = 0; w < wv; ++w) wo += ws4[w];
  if (i < NN) {
    cursor[i] = s - v + wo + bsum[blockIdx.x];
    degf[i] = (float)v;
  }
}

// scatter_pay: 2 threads/edge — even lane does the atomic, broadcasts pos to
// its partner; each thread loads/converts/writes HALF the ea row (64B load,
// 32B store). Doubles MLP on the latency-bound random-write phase.
// Also zeroes h32 (EE*2 threads x 8B == NN*HH f32 exactly).
__global__ __launch_bounds__(256)
void scatter_pay(const int* __restrict__ ei, const float* __restrict__ edge_attr,
                 int* __restrict__ cursor, u32* __restrict__ sd, u16* __restrict__ eap,
                 float* __restrict__ h32)
{
  int t = blockIdx.x * 256 + threadIdx.x;
  if (t < EE * 2) {
    f32x2 z2 = (f32x2){0.f, 0.f};
    *reinterpret_cast<f32x2*>(h32 + (size_t)t * 2) = z2;
  }
  int e = t >> 1, q = t & 1;
  if (e >= EE) return;
  const int lane = threadIdx.x & 63;

  int s = ei[e];
  int d = ei[EE + e];
  const f32x4* pa = reinterpret_cast<const f32x4*>(edge_attr + (size_t)e * EDIM + q * 16);
  f32x4 v[4];
#pragma unroll
  for (int k = 0; k < 4; ++k) v[k] = pa[k];
  u16x8 o[2];
#pragma unroll
  for (int k = 0; k < 2; ++k)
#pragma unroll
    for (int j = 0; j < 4; ++j) {
      o[k][j] = f2bf(v[2 * k][j]);
      o[k][4 + j] = f2bf(v[2 * k + 1][j]);
    }
  int posv = (q == 0) ? atomicAdd(&cursor[d], 1) : 0;
  int pos = __shfl(posv, lane & 62, 64);   // broadcast even lane of the pair
  if (q == 0) sd[pos] = ((u32)s << 16) | (u32)d;
  u16* po = eap + (size_t)pos * EDIM + q * 16;
#pragma unroll
  for (int k = 0; k < 2; ++k)
    *reinterpret_cast<u16x8*>(po + k * 8) = o[k];
}

// ------------------------------- node enc: h0 (f32) -> p0 (split GEMM) -----
// p storage is bf16, PERMUTED: p[node*64 + r16*4 + nt] == logical col nt*16+r16.
__global__ __launch_bounds__(256, 2)
void node_enc(const float* __restrict__ x, const u16* __restrict__ nWf,
              const float* __restrict__ node_b, const u16* __restrict__ W1T,
              u16* __restrict__ p)
{
  __shared__ __align__(16) char ebuf[64 * 272];   // Xs (u16 LDX) / Hs (f32 LHS)
  u16* Xs = reinterpret_cast<u16*>(ebuf);
  float* Hs = reinterpret_cast<float*>(ebuf);
  const int tid = threadIdx.x;
  const int base = blockIdx.x * 64;
  const int lane = tid & 63, wv = tid >> 6;
  const int r16 = lane & 15, kg = lane >> 4;

  bf16x8 Bf[4][4];
#pragma unroll
  for (int kk = 0; kk < 4; ++kk)
#pragma unroll
    for (int nt = 0; nt < 4; ++nt)
      Bf[kk][nt] = *reinterpret_cast<const bf16x8*>(nWf + ((kk * 4 + nt) * 64 + lane) * 8);
  float bias[4];
#pragma unroll
  for (int nt = 0; nt < 4; ++nt) bias[nt] = node_b[nt * 16 + r16];

#pragma unroll
  for (int it = 0; it < 4; ++it) {
    int s = it * 256 + tid;
    int r = s >> 4, c = (s & 15) * 8;
    int node = base + r;
    u16x8 o;
    if (node < NN) {
      const f32x4* px = reinterpret_cast<const f32x4*>(x + (size_t)node * NDIM + c);
      f32x4 v0 = px[0], v1 = px[1];
#pragma unroll
      for (int j = 0; j < 4; ++j) { o[j] = f2bf(v0[j]); o[4 + j] = f2bf(v1[j]); }
    } else {
#pragma unroll
      for (int j = 0; j < 8; ++j) o[j] = 0;
    }
    *reinterpret_cast<u16x8*>(&Xs[r * LDX + c]) = o;
  }
  __syncthreads();

  f32x4 acc[4];
#pragma unroll
  for (int nt = 0; nt < 4; ++nt) acc[nt] = (f32x4){0.f, 0.f, 0.f, 0.f};
#pragma unroll
  for (int kk = 0; kk < 4; ++kk) {
    bf16x8 a = *reinterpret_cast<const bf16x8*>(&Xs[(wv * 16 + r16) * LDX + kk * 32 + kg * 8]);
#pragma unroll
    for (int nt = 0; nt < 4; ++nt)
      acc[nt] = __builtin_amdgcn_mfma_f32_16x16x32_bf16(a, Bf[kk][nt], acc[nt], 0, 0, 0);
  }
  __syncthreads();

#pragma unroll
  for (int nt = 0; nt < 4; ++nt)
#pragma unroll
    for (int j = 0; j < 4; ++j)
      Hs[(wv * 16 + kg * 4 + j) * LHS + nt * 16 + r16] = acc[nt][j] + bias[nt];
  __syncthreads();

  bf16x8 Bt[2][4];
#pragma unroll
  for (int kk = 0; kk < 2; ++kk)
#pragma unroll
    for (int nt = 0; nt < 4; ++nt)
      Bt[kk][nt] = *reinterpret_cast<const bf16x8*>(W1T + ((kk * 4 + nt) * 64 + lane) * 8);

  f32x4 acc2[4];
#pragma unroll
  for (int nt = 0; nt < 4; ++nt) acc2[nt] = (f32x4){0.f, 0.f, 0.f, 0.f};
#pragma unroll
  for (int kk = 0; kk < 2; ++kk) {
    const f32x4* pa = reinterpret_cast<const f32x4*>(&Hs[(wv * 16 + r16) * LHS + kk * 32 + kg * 8]);
    f32x4 a0 = pa[0], a1 = pa[1];
    bf16x8 hi, lo;
    split8(a0, a1, hi, lo);
#pragma unroll
    for (int nt = 0; nt < 4; ++nt) {
      acc2[nt] = __builtin_amdgcn_mfma_f32_16x16x32_bf16(hi, Bt[kk][nt], acc2[nt], 0, 0, 0);
      acc2[nt] = __builtin_amdgcn_mfma_f32_16x16x32_bf16(lo, Bt[kk][nt], acc2[nt], 0, 0, 0);
    }
  }
#pragma unroll
  for (int j = 0; j < 4; ++j) {
    int node = base + wv * 16 + kg * 4 + j;
    if (node < NN) {
      u16x4 w4;
#pragma unroll
      for (int nt = 0; nt < 4; ++nt) w4[nt] = f2bf(acc2[nt][j]);
      *reinterpret_cast<u16x4*>(p + (size_t)node * HH + r16 * 4) = w4;
    }
  }
}

// --------------------- message: relu(p_src+p_dst+ea@W1e'+b1'), aggregate ---
__global__ __launch_bounds__(256, 8)
void msg2(const u32* __restrict__ sd, const u16* __restrict__ eap,
          const u16* __restrict__ p, float* __restrict__ h32,
          const u16* __restrict__ W1E, const float* __restrict__ b1p, int layer)
{
  __shared__ float Sm[64 * SMS];
  __shared__ u32 sd_s[64];
  __shared__ int segpos[64];
  __shared__ int segn;

  const int tid = threadIdx.x;
  const int base = blockIdx.x * 64;
  const int lane = tid & 63, wv = tid >> 6;
  const int r16 = lane & 15, kg = lane >> 4;

  if (tid < 64) sd_s[tid] = sd[base + tid];

  bf16x8 B1[4];
  const u16* w1 = W1E + layer * 2048;
#pragma unroll
  for (int nt = 0; nt < 4; ++nt)
    B1[nt] = *reinterpret_cast<const bf16x8*>(w1 + (nt * 64 + lane) * 8);
  float b1v[4];
#pragma unroll
  for (int nt = 0; nt < 4; ++nt) b1v[nt] = b1p[layer * HH + nt * 16 + r16];

  // A-frag: pre-sorted bf16 edge_attr, direct 16B streaming load
  bf16x8 af = *reinterpret_cast<const bf16x8*>(
      eap + (size_t)(base + wv * 16 + r16) * EDIM + kg * 8);
  __syncthreads();

  if (wv == 0) {
    int dme = sd_s[lane] & 0xffff;
    int dpr = (lane > 0) ? (sd_s[lane - 1] & 0xffff) : -1;
    bool st = (dme != dpr);
    unsigned long long m = __ballot(st);
    if (st) {
      int rk = __popcll(m & ((1ull << lane) - 1ull));
      segpos[rk] = lane;
    }
    if (lane == 0) segn = __popcll(m);
  }

  // C init: p[src]+p[dst]+b1' via permuted-layout bf16x4 gathers (8B each)
  f32x4 acc[4];
#pragma unroll
  for (int j = 0; j < 4; ++j) {
    int row = wv * 16 + kg * 4 + j;
    u32 w = sd_s[row];
    const u16x4 a4 = *reinterpret_cast<const u16x4*>(p + (size_t)(w >> 16) * HH + r16 * 4);
    const u16x4 b4 = *reinterpret_cast<const u16x4*>(p + (size_t)(w & 0xffff) * HH + r16 * 4);
#pragma unroll
    for (int nt = 0; nt < 4; ++nt)
      acc[nt][j] = bf2f(a4[nt]) + bf2f(b4[nt]) + b1v[nt];
  }

#pragma unroll
  for (int nt = 0; nt < 4; ++nt)
    acc[nt] = __builtin_amdgcn_mfma_f32_16x16x32_bf16(af, B1[nt], acc[nt], 0, 0, 0);

#pragma unroll
  for (int nt = 0; nt < 4; ++nt)
#pragma unroll
    for (int j = 0; j < 4; ++j)
      Sm[(wv * 16 + kg * 4 + j) * SMS + nt * 16 + r16] = fmaxf(acc[nt][j], 0.f);
  __syncthreads();

  int ns = segn;
  for (int s = wv; s < ns; s += 4) {
    int r0 = segpos[s];
    int r1 = (s + 1 < ns) ? segpos[s + 1] : 64;
    float sum = 0.f;
    for (int r = r0; r < r1; ++r) sum += Sm[r * SMS + lane];
    unsafeAtomicAdd(&h32[(size_t)(sd_s[r0] & 0xffff) * HH + lane], sum);
  }
}

// ------ node update: h = hsum@W2 + deg*b2 (split); p' = h@W1top' (split);
// ------ on layer 3: r_src = h@fin_W1_top, r_dst = h@fin_W1_bot + fin_b1 ----
__global__ __launch_bounds__(256, 3)
void node_update(float* __restrict__ h32, const float* __restrict__ degf,
                 const u16* __restrict__ W2f, const float* __restrict__ b2a,
                 const u16* __restrict__ W1T, u16* __restrict__ p,
                 const u16* __restrict__ fWs, const u16* __restrict__ fWd,
                 const float* __restrict__ fin_b1,
                 u16* __restrict__ r_src, u16* __restrict__ r_dst, int layer)
{
  __shared__ __align__(16) float Hs[64 * LHS];
  const int tid = threadIdx.x;
  const int base = blockIdx.x * 64;
  const int lane = tid & 63, wv = tid >> 6;
  const int r16 = lane & 15, kg = lane >> 4;

#pragma unroll
  for (int it = 0; it < 2; ++it) {
    int s = it * 256 + tid;
    int r = s >> 3, c = (s & 7) * 8;
    int node = base + r;
    f32x4 v0 = (f32x4){0.f, 0.f, 0.f, 0.f}, v1 = v0;
    if (node < NN) {
      f32x4* ph = reinterpret_cast<f32x4*>(h32 + (size_t)node * HH + c);
      v0 = ph[0]; v1 = ph[1];
      f32x4 z = (f32x4){0.f, 0.f, 0.f, 0.f};
      ph[0] = z; ph[1] = z;
    }
    *reinterpret_cast<f32x4*>(&Hs[r * LHS + c]) = v0;
    *reinterpret_cast<f32x4*>(&Hs[r * LHS + c + 4]) = v1;
  }

  bf16x8 B2[2][4];
  const u16* w2 = W2f + layer * 4096;
#pragma unroll
  for (int kk = 0; kk < 2; ++kk)
#pragma unroll
    for (int nt = 0; nt < 4; ++nt)
      B2[kk][nt] = *reinterpret_cast<const bf16x8*>(w2 + ((kk * 4 + nt) * 64 + lane) * 8);
  float b2v[4];
#pragma unroll
  for (int nt = 0; nt < 4; ++nt) b2v[nt] = b2a[layer * HH + nt * 16 + r16];
  float degj[4];
#pragma unroll
  for (int j = 0; j < 4; ++j) {
    int node = base + wv * 16 + kg * 4 + j;
    degj[j] = (node < NN) ? degf[node] : 0.f;
  }
  __syncthreads();

  // h = hsum @ W2 + deg*b2, split-precision A
  f32x4 acc[4];
#pragma unroll
  for (int nt = 0; nt < 4; ++nt)
#pragma unroll
    for (int j = 0; j < 4; ++j) acc[nt][j] = degj[j] * b2v[nt];
#pragma unroll
  for (int kk = 0; kk < 2; ++kk) {
    const f32x4* pa = reinterpret_cast<const f32x4*>(&Hs[(wv * 16 + r16) * LHS + kk * 32 + kg * 8]);
    f32x4 a0 = pa[0], a1 = pa[1];
    bf16x8 hi, lo;
    split8(a0, a1, hi, lo);
#pragma unroll
    for (int nt = 0; nt < 4; ++nt) {
      acc[nt] = __builtin_amdgcn_mfma_f32_16x16x32_bf16(hi, B2[kk][nt], acc[nt], 0, 0, 0);
      acc[nt] = __builtin_amdgcn_mfma_f32_16x16x32_bf16(lo, B2[kk][nt], acc[nt], 0, 0, 0);
    }
  }

  __syncthreads();
#pragma unroll
  for (int nt = 0; nt < 4; ++nt)
#pragma unroll
    for (int j = 0; j < 4; ++j)
      Hs[(wv * 16 + kg * 4 + j) * LHS + nt * 16 + r16] = acc[nt][j];
  __syncthreads();

  if (layer == 3) {
    bf16x8 Bs[2][4], Bd[2][4];
#pragma unroll
    for (int kk = 0; kk < 2; ++kk)
#pragma unroll
      for (int nt = 0; nt < 4; ++nt) {
        Bs[kk][nt] = *reinterpret_cast<const bf16x8*>(fWs + ((kk * 4 + nt) * 64 + lane) * 8);
        Bd[kk][nt] = *reinterpret_cast<const bf16x8*>(fWd + ((kk * 4 + nt) * 64 + lane) * 8);
      }
    float fb1v[4];
#pragma unroll
    for (int nt = 0; nt < 4; ++nt) fb1v[nt] = fin_b1[nt * 16 + r16];

    f32x4 as_[4], ad_[4];
#pragma unroll
    for (int nt = 0; nt < 4; ++nt) {
      as_[nt] = (f32x4){0.f, 0.f, 0.f, 0.f};
#pragma unroll
      for (int j = 0; j < 4; ++j) ad_[nt][j] = fb1v[nt];
    }
#pragma unroll
    for (int kk = 0; kk < 2; ++kk) {
      const f32x4* pa = reinterpret_cast<const f32x4*>(&Hs[(wv * 16 + r16) * LHS + kk * 32 + kg * 8]);
      f32x4 a0 = pa[0], a1 = pa[1];
      bf16x8 hi, lo;
      split8(a0, a1, hi, lo);
#pragma unroll
      for (int nt = 0; nt < 4; ++nt) {
        as_[nt] = __builtin_amdgcn_mfma_f32_16x16x32_bf16(hi, Bs[kk][nt], as_[nt], 0, 0, 0);
        as_[nt] = __builtin_amdgcn_mfma_f32_16x16x32_bf16(lo, Bs[kk][nt], as_[nt], 0, 0, 0);
        ad_[nt] = __builtin_amdgcn_mfma_f32_16x16x32_bf16(hi, Bd[kk][nt], ad_[nt], 0, 0, 0);
        ad_[nt] = __builtin_amdgcn_mfma_f32_16x16x32_bf16(lo, Bd[kk][nt], ad_[nt], 0, 0, 0);
      }
    }
#pragma unroll
    for (int j = 0; j < 4; ++j) {
      int node = base + wv * 16 + kg * 4 + j;
      if (node < NN) {
#pragma unroll
        for (int nt = 0; nt < 4; ++nt) {
          r_src[(size_t)node * HH + nt * 16 + r16] = f2bf(as_[nt][j]);
          r_dst[(size_t)node * HH + nt * 16 + r16] = f2bf(ad_[nt][j]);
        }
      }
    }
    return;
  }

  // p' = h @ W1top[layer+1] (split), stored bf16 permuted
  bf16x8 Bt[2][4];
  const u16* wt = W1T + (layer + 1) * 4096;
#pragma unroll
  for (int kk = 0; kk < 2; ++kk)
#pragma unroll
    for (int nt = 0; nt < 4; ++nt)
      Bt[kk][nt] = *reinterpret_cast<const bf16x8*>(wt + ((kk * 4 + nt) * 64 + lane) * 8);

  f32x4 acc2[4];
#pragma unroll
  for (int nt = 0; nt < 4; ++nt) acc2[nt] = (f32x4){0.f, 0.f, 0.f, 0.f};
#pragma unroll
  for (int kk = 0; kk < 2; ++kk) {
    const f32x4* pa = reinterpret_cast<const f32x4*>(&Hs[(wv * 16 + r16) * LHS + kk * 32 + kg * 8]);
    f32x4 a0 = pa[0], a1 = pa[1];
    bf16x8 hi, lo;
    split8(a0, a1, hi, lo);
#pragma unroll
    for (int nt = 0; nt < 4; ++nt) {
      acc2[nt] = __builtin_amdgcn_mfma_f32_16x16x32_bf16(hi, Bt[kk][nt], acc2[nt], 0, 0, 0);
      acc2[nt] = __builtin_amdgcn_mfma_f32_16x16x32_bf16(lo, Bt[kk][nt], acc2[nt], 0, 0, 0);
    }
  }
#pragma unroll
  for (int j = 0; j < 4; ++j) {
    int node = base + wv * 16 + kg * 4 + j;
    if (node < NN) {
      u16x4 w4;
#pragma unroll
      for (int nt = 0; nt < 4; ++nt) w4[nt] = f2bf(acc2[nt][j]);
      *reinterpret_cast<u16x4*>(p + (size_t)node * HH + r16 * 4) = w4;
    }
  }
}

// -- final: 4 threads/edge, original order; coalesced 128B row-gathers ------
__global__ __launch_bounds__(256)
void final2(const int* __restrict__ ei, const u16* __restrict__ r_src,
            const u16* __restrict__ r_dst, const float* __restrict__ fin_W2,
            const float* __restrict__ fin_b2, float* __restrict__ out)
{
  __shared__ float w2s[64];
  const int tid = threadIdx.x;
  if (tid < 64) w2s[tid] = fin_W2[tid];
  __syncthreads();
  int t = blockIdx.x * 256 + tid;
  int e = t >> 2, q = t & 3;            // 4 threads per edge, 16 cols each
  if (e >= EE) return;
  int s = ei[e], d = ei[EE + e];
  const u16x8* prs = reinterpret_cast<const u16x8*>(r_src + (size_t)s * HH + q * 16);
  const u16x8* prd = reinterpret_cast<const u16x8*>(r_dst + (size_t)d * HH + q * 16);
  float acc = 0.f;
#pragma unroll
  for (int h = 0; h < 2; ++h) {
    u16x8 a = prs[h], b = prd[h];
#pragma unroll
    for (int j = 0; j < 8; ++j) {
      float v = bf2f(a[j]) + bf2f(b[j]);
      acc += fmaxf(v, 0.f) * w2s[q * 16 + h * 8 + j];
    }
  }
  acc += __shfl_xor(acc, 1, 64);
  acc += __shfl_xor(acc, 2, 64);
  if (q == 0) out[e] = acc + fin_b2[0];
}

// ---------------------------------------------------------------- launch ---
extern "C" void kernel_launch(void* const* d_in, const int* in_sizes, int n_in,
                              void* d_out, int out_size, void* d_ws, size_t ws_size,
                              hipStream_t stream)
{
  const float* x      = (const float*)d_in[0];
  const float* eattr  = (const float*)d_in[1];
  const int*   ei     = (const int*)d_in[2];
  const float* node_W = (const float*)d_in[3];
  const float* node_b = (const float*)d_in[4];
  const float* edge_W = (const float*)d_in[5];
  const float* edge_b = (const float*)d_in[6];
  const float* W1     = (const float*)d_in[7];
  const float* b1     = (const float*)d_in[8];
  const float* W2     = (const float*)d_in[9];
  const float* b2     = (const float*)d_in[10];
  const float* fin_W1 = (const float*)d_in[11];
  const float* fin_b1 = (const float*)d_in[12];
  const float* fin_W2 = (const float*)d_in[13];
  const float* fin_b2 = (const float*)d_in[14];

  char* ws    = (char*)d_ws;
  float* h32  = (float*)(ws + OFF_H32);
  u16* p      = (u16*)(ws + OFF_P);
  u16* r_src  = (u16*)(ws + OFF_RS);
  u16* r_dst  = (u16*)(ws + OFF_RD);
  u16* nWf    = (u16*)(ws + OFF_NWF);
  u16* W1T    = (u16*)(ws + OFF_W1T);
  u16* W1E    = (u16*)(ws + OFF_W1E);
  u16* W2f    = (u16*)(ws + OFF_W2F);
  u16* fWs    = (u16*)(ws + OFF_FWS);
  u16* fWd    = (u16*)(ws + OFF_FWD);
  float* b1p  = (float*)(ws + OFF_B1P);
  int* cursor = (int*)(ws + OFF_CUR);
  float* degf = (float*)(ws + OFF_DEG);
  int* bsum   = (int*)(ws + OFF_BSUM);
  u32* sd     = (u32*)(ws + OFF_SD);
  u16* eap    = (u16*)(ws + OFF_EAP);

  zero_cursor<<<NBLK, 256, 0, stream>>>(cursor);
  setup_kernel<<<6, 256, 0, stream>>>(node_W, edge_W, edge_b, W1, b1, W2, fin_W1,
                                      nWf, W1T, W1E, W2f, fWs, fWd, b1p);
  node_enc<<<NB64, 256, 0, stream>>>(x, nWf, node_b, W1T, p);

  hist_kernel<<<(EE + 255) / 256, 256, 0, stream>>>(ei, cursor);
  chunk_sum<<<NBLK, 256, 0, stream>>>(cursor, bsum);
  scan_small<<<1, 64, 0, stream>>>(bsum);
  scan_write<<<NBLK, 256, 0, stream>>>(cursor, bsum, degf);
  scatter_pay<<<(EE * 2 + 255) / 256, 256, 0, stream>>>(ei, eattr, cursor, sd, eap, h32);

  for (int l = 0; l < 4; ++l) {
    msg2<<<EE / 64, 256, 0, stream>>>(sd, eap, p, h32, W1E, b1p, l);
    node_update<<<NB64, 256, 0, stream>>>(h32, degf, W2f, b2, W1T, p,
                                          fWs, fWd, fin_b1, r_src, r_dst, l);
  }
  final2<<<(EE * 4 + 255) / 256, 256, 0, stream>>>(ei, r_src, r_dst,
                                                   fin_W2, fin_b2, (float*)d_out);
}